// Round 2
// baseline (1128.458 us; speedup 1.0000x reference)
//
#include <hip/hip_runtime.h>
#include <math.h>

#define N_NODES 10000
#define N_EDGES 320000
#define NFEAT 512
#define NHID 256
#define NCLASS 64
#define N_LAYERS 8
#define ALPHA_C 0.1f
#define THETA_C 0.5f
#define BN_EPS 1e-5f

// ---------------- init: deg=1 (self loop), cursor=0, stats=0 ----------------
__global__ void init_kernel(int* __restrict__ deg, int* __restrict__ cursor,
                            float* __restrict__ stats) {
    int i = blockIdx.x * 256 + threadIdx.x;
    if (i < N_NODES) { deg[i] = 1; cursor[i] = 0; }
    if (i < N_LAYERS * 2 * NHID) stats[i] = 0.f;
}

// ---------------- degree histogram over col ----------------
__global__ void deg_count(const int* __restrict__ col, int* __restrict__ deg) {
    int e = blockIdx.x * 256 + threadIdx.x;
    if (e < N_EDGES) atomicAdd(&deg[col[e]], 1);
}

// ---------------- dinv = rsqrt(deg) ----------------
__global__ void dinv_kernel(const int* __restrict__ deg, float* __restrict__ dinv) {
    int i = blockIdx.x * 256 + threadIdx.x;
    if (i < N_NODES) dinv[i] = rsqrtf((float)deg[i]);
}

// ---------------- single-block exclusive scan of (deg-1) -> offs[N+1] ----------------
__global__ void scan_kernel(const int* __restrict__ deg, int* __restrict__ offs) {
    __shared__ int sm[256];
    __shared__ int carry_s;
    int tid = threadIdx.x;
    if (tid == 0) carry_s = 0;
    __syncthreads();
    for (int base = 0; base < N_NODES; base += 256) {
        int i = base + tid;
        int cnt = (i < N_NODES) ? (deg[i] - 1) : 0;
        sm[tid] = cnt;
        __syncthreads();
        #pragma unroll
        for (int off = 1; off < 256; off <<= 1) {
            int v = (tid >= off) ? sm[tid - off] : 0;
            __syncthreads();
            sm[tid] += v;
            __syncthreads();
        }
        int excl = sm[tid] - cnt;
        int carry = carry_s;
        if (i < N_NODES) offs[i] = carry + excl;
        int total = sm[255];
        __syncthreads();
        if (tid == 0) carry_s = carry + total;
        __syncthreads();
    }
    if (tid == 0) offs[N_NODES] = carry_s;
}

// ---------------- scatter edges into CSR buckets (by col) ----------------
__global__ void scatter_kernel(const int* __restrict__ row, const int* __restrict__ col,
                               const float* __restrict__ dinv, const int* __restrict__ offs,
                               int* __restrict__ cursor, int2* __restrict__ csr) {
    int e = blockIdx.x * 256 + threadIdx.x;
    if (e >= N_EDGES) return;
    int c = col[e], r = row[e];
    int pos = offs[c] + atomicAdd(&cursor[c], 1);
    float w = dinv[r] * dinv[c];
    csr[pos] = make_int2(r, __float_as_int(w));
}

// ---------------- SpMM + self-loop + alpha blend: p = 0.9*(A_hat h) + 0.1*x0 ----------------
// one wave per node; 64 lanes x float4 = 256 feats
__global__ __launch_bounds__(256)
void spmm_blend(const float4* __restrict__ h4, const float4* __restrict__ x04,
                const int* __restrict__ offs, const int2* __restrict__ csr,
                const float* __restrict__ dinv, float4* __restrict__ p4) {
    int wid = threadIdx.x >> 6;
    int lane = threadIdx.x & 63;
    int v = blockIdx.x * 4 + wid;
    if (v >= N_NODES) return;
    float dv = dinv[v];
    float sw = dv * dv;
    float4 acc = h4[(size_t)v * 64 + lane];
    acc.x *= sw; acc.y *= sw; acc.z *= sw; acc.w *= sw;
    int beg = offs[v], end = offs[v + 1];
    for (int e = beg; e < end; ++e) {
        int2 sv = csr[e];
        float w = __int_as_float(sv.y);
        float4 hv = h4[(size_t)sv.x * 64 + lane];
        acc.x = fmaf(w, hv.x, acc.x);
        acc.y = fmaf(w, hv.y, acc.y);
        acc.z = fmaf(w, hv.z, acc.z);
        acc.w = fmaf(w, hv.w, acc.w);
    }
    float4 xv = x04[(size_t)v * 64 + lane];
    float4 r;
    r.x = 0.9f * acc.x + 0.1f * xv.x;
    r.y = 0.9f * acc.y + 0.1f * xv.y;
    r.z = 0.9f * acc.z + 0.1f * xv.z;
    r.w = 0.9f * acc.w + 0.1f * xv.w;
    p4[(size_t)v * 64 + lane] = r;
}

// ---------------- generic fp32 GEMM: C = act(alpha*(A@B) + rcoef*A[.,c] + bias) ----------------
// BM=BN=64, BK=16, 256 threads, 4x4 microtile
template<bool BIAS, bool RELU, bool RESID>
__global__ __launch_bounds__(256)
void gemm64(const float* __restrict__ A, const float* __restrict__ B,
            const float* __restrict__ bias, float* __restrict__ C,
            int M, int Nc, int K, float alpha, float rcoef) {
    __shared__ float As[16][68];
    __shared__ float Bs[16][68];
    int tid = threadIdx.x;
    int tc = tid & 15, tr = tid >> 4;
    int brow = blockIdx.x * 64, bcol = blockIdx.y * 64;
    float acc[4][4] = {};
    int arow = tid >> 2;            // 0..63
    int ak = (tid & 3) * 4;         // 0,4,8,12
    int bkrow = tid >> 4;           // 0..15
    int bcol4 = (tid & 15) * 4;     // 0..60

    for (int k0 = 0; k0 < K; k0 += 16) {
        int gr = brow + arow;
        float4 av = (gr < M) ? *(const float4*)&A[(size_t)gr * K + k0 + ak]
                             : make_float4(0.f, 0.f, 0.f, 0.f);
        As[ak + 0][arow] = av.x;
        As[ak + 1][arow] = av.y;
        As[ak + 2][arow] = av.z;
        As[ak + 3][arow] = av.w;
        float4 bv = *(const float4*)&B[(size_t)(k0 + bkrow) * Nc + bcol + bcol4];
        *(float4*)&Bs[bkrow][bcol4] = bv;
        __syncthreads();
        #pragma unroll
        for (int kk = 0; kk < 16; ++kk) {
            float4 a = *(const float4*)&As[kk][tr * 4];
            float4 b = *(const float4*)&Bs[kk][tc * 4];
            acc[0][0] = fmaf(a.x, b.x, acc[0][0]);
            acc[0][1] = fmaf(a.x, b.y, acc[0][1]);
            acc[0][2] = fmaf(a.x, b.z, acc[0][2]);
            acc[0][3] = fmaf(a.x, b.w, acc[0][3]);
            acc[1][0] = fmaf(a.y, b.x, acc[1][0]);
            acc[1][1] = fmaf(a.y, b.y, acc[1][1]);
            acc[1][2] = fmaf(a.y, b.z, acc[1][2]);
            acc[1][3] = fmaf(a.y, b.w, acc[1][3]);
            acc[2][0] = fmaf(a.z, b.x, acc[2][0]);
            acc[2][1] = fmaf(a.z, b.y, acc[2][1]);
            acc[2][2] = fmaf(a.z, b.z, acc[2][2]);
            acc[2][3] = fmaf(a.z, b.w, acc[2][3]);
            acc[3][0] = fmaf(a.w, b.x, acc[3][0]);
            acc[3][1] = fmaf(a.w, b.y, acc[3][1]);
            acc[3][2] = fmaf(a.w, b.z, acc[3][2]);
            acc[3][3] = fmaf(a.w, b.w, acc[3][3]);
        }
        __syncthreads();
    }

    int r0 = brow + tr * 4, c0 = bcol + tc * 4;
    float4 b4 = make_float4(0.f, 0.f, 0.f, 0.f);
    if (BIAS) b4 = *(const float4*)&bias[c0];
    #pragma unroll
    for (int i = 0; i < 4; ++i) {
        int r = r0 + i;
        if (r >= M) continue;
        float4 resid = make_float4(0.f, 0.f, 0.f, 0.f);
        if (RESID) resid = *(const float4*)&A[(size_t)r * K + c0];  // K==Nc in this mode
        float4 o;
        o.x = fmaf(alpha, acc[i][0], fmaf(rcoef, resid.x, b4.x));
        o.y = fmaf(alpha, acc[i][1], fmaf(rcoef, resid.y, b4.y));
        o.z = fmaf(alpha, acc[i][2], fmaf(rcoef, resid.z, b4.z));
        o.w = fmaf(alpha, acc[i][3], fmaf(rcoef, resid.w, b4.w));
        if (RELU) {
            o.x = fmaxf(o.x, 0.f); o.y = fmaxf(o.y, 0.f);
            o.z = fmaxf(o.z, 0.f); o.w = fmaxf(o.w, 0.f);
        }
        *(float4*)&C[(size_t)r * Nc + c0] = o;
    }
}

// ---------------- BN column stats: sum, sumsq ----------------
__global__ __launch_bounds__(256)
void bn_stats(const float* __restrict__ out, float* __restrict__ stats) {
    int f = threadIdx.x;
    int chunk = (N_NODES + gridDim.x - 1) / gridDim.x;
    int r0 = blockIdx.x * chunk;
    int r1 = min(r0 + chunk, N_NODES);
    float s = 0.f, s2 = 0.f;
    for (int r = r0; r < r1; ++r) {
        float v = out[(size_t)r * NHID + f];
        s += v; s2 = fmaf(v, v, s2);
    }
    atomicAdd(&stats[f], s);
    atomicAdd(&stats[NHID + f], s2);
}

// ---------------- BN finalize: AB[f]=gamma*rstd, AB[256+f]=beta-mu*gamma*rstd ----------------
__global__ void bn_final(const float* __restrict__ stats, const float* __restrict__ g,
                         const float* __restrict__ b, float* __restrict__ AB) {
    int f = threadIdx.x;
    float mu = stats[f] * (1.f / N_NODES);
    float var = stats[NHID + f] * (1.f / N_NODES) - mu * mu;
    float rs = rsqrtf(var + BN_EPS);
    float a = g[f] * rs;
    AB[f] = a;
    AB[NHID + f] = b[f] - mu * a;
}

// ---------------- BN apply + relu: h = max(out*A + B, 0) ----------------
__global__ __launch_bounds__(256)
void bn_apply(const float4* __restrict__ out4, const float* __restrict__ AB,
              float4* __restrict__ h4) {
    int i = blockIdx.x * 256 + threadIdx.x;   // over N_NODES*64
    if (i >= N_NODES * 64) return;
    int f4 = (i & 63) * 4;
    float4 v = out4[i];
    float4 r;
    r.x = fmaxf(fmaf(v.x, AB[f4 + 0], AB[NHID + f4 + 0]), 0.f);
    r.y = fmaxf(fmaf(v.y, AB[f4 + 1], AB[NHID + f4 + 1]), 0.f);
    r.z = fmaxf(fmaf(v.z, AB[f4 + 2], AB[NHID + f4 + 2]), 0.f);
    r.w = fmaxf(fmaf(v.w, AB[f4 + 3], AB[NHID + f4 + 3]), 0.f);
    h4[i] = r;
}

// ---------------- host ----------------
static inline size_t align_up(size_t x, size_t a) { return (x + a - 1) & ~(a - 1); }

extern "C" void kernel_launch(void* const* d_in, const int* in_sizes, int n_in,
                              void* d_out, int out_size, void* d_ws, size_t ws_size,
                              hipStream_t stream) {
    const float* x       = (const float*)d_in[0];
    const int*   ei      = (const int*)d_in[1];   // [2, E]
    const float* lin0_w  = (const float*)d_in[2];
    const float* lin0_b  = (const float*)d_in[3];
    const float* lin1_w  = (const float*)d_in[4];
    const float* lin1_b  = (const float*)d_in[5];
    const float* conv_w  = (const float*)d_in[6]; // [8,256,256]
    const float* bn_g    = (const float*)d_in[7];
    const float* bn_b    = (const float*)d_in[8];
    const int* rowp = ei;
    const int* colp = ei + N_EDGES;
    float* outp = (float*)d_out;

    char* ws = (char*)d_ws;
    size_t off = 0;
    auto alloc = [&](size_t bytes) { size_t o = off; off = align_up(off + bytes, 256); return ws + o; };
    int*   deg    = (int*)alloc(N_NODES * 4);
    int*   cursor = (int*)alloc(N_NODES * 4);
    int*   offs   = (int*)alloc((N_NODES + 1) * 4);
    float* dinv   = (float*)alloc(N_NODES * 4);
    int2*  csr    = (int2*)alloc((size_t)N_EDGES * 8);
    float* x0     = (float*)alloc((size_t)N_NODES * NHID * 4);
    float* h      = (float*)alloc((size_t)N_NODES * NHID * 4);
    float* p      = (float*)alloc((size_t)N_NODES * NHID * 4);
    float* outb   = (float*)alloc((size_t)N_NODES * NHID * 4);
    float* stats  = (float*)alloc(N_LAYERS * 2 * NHID * 4);
    float* AB     = (float*)alloc(2 * NHID * 4);
    (void)ws_size; (void)n_in; (void)in_sizes; (void)out_size;

    // graph preprocessing
    init_kernel<<<40, 256, 0, stream>>>(deg, cursor, stats);
    deg_count<<<(N_EDGES + 255) / 256, 256, 0, stream>>>(colp, deg);
    dinv_kernel<<<(N_NODES + 255) / 256, 256, 0, stream>>>(deg, dinv);
    scan_kernel<<<1, 256, 0, stream>>>(deg, offs);
    scatter_kernel<<<(N_EDGES + 255) / 256, 256, 0, stream>>>(rowp, colp, dinv, offs, cursor, csr);

    // lin0: x0 = relu(x @ W0 + b0)
    gemm64<true, true, false><<<dim3(157, 4), 256, 0, stream>>>(
        x, lin0_w, lin0_b, x0, N_NODES, NHID, NFEAT, 1.f, 0.f);

    const float* h_in = x0;
    for (int l = 0; l < N_LAYERS; ++l) {
        float beta = logf(THETA_C / (float)(l + 1) + 1.0f);
        spmm_blend<<<2500, 256, 0, stream>>>(
            (const float4*)h_in, (const float4*)x0, offs, csr, dinv, (float4*)p);
        gemm64<false, false, true><<<dim3(157, 4), 256, 0, stream>>>(
            p, conv_w + (size_t)l * NHID * NHID, nullptr, outb,
            N_NODES, NHID, NHID, beta, 1.f - beta);
        bn_stats<<<80, 256, 0, stream>>>(outb, stats + l * 2 * NHID);
        bn_final<<<1, 256, 0, stream>>>(stats + l * 2 * NHID, bn_g + l * NHID, bn_b + l * NHID, AB);
        bn_apply<<<2500, 256, 0, stream>>>((const float4*)outb, AB, (float4*)h);
        h_in = h;
    }

    // lin1: out = h @ W1 + b1
    gemm64<true, false, false><<<dim3(157, 1), 256, 0, stream>>>(
        h, lin1_w, lin1_b, outp, N_NODES, NCLASS, NHID, 1.f, 0.f);
}

// Round 4
// 871.077 us; speedup vs baseline: 1.2955x; 1.2955x over previous
//
#include <hip/hip_runtime.h>
#include <math.h>

#define N_NODES 10000
#define N_EDGES 320000
#define NFEAT 512
#define NHID 256
#define NCLASS 64
#define N_LAYERS 8
#define BN_EPS 1e-5f

typedef unsigned short u16;
typedef __attribute__((ext_vector_type(8))) short short8v;
typedef __attribute__((ext_vector_type(4))) float f32x4;

__device__ __forceinline__ u16 bf_hi_bits(float f) {
    unsigned u = __float_as_uint(f);
    unsigned r = (u + 0x7fffu + ((u >> 16) & 1u)) >> 16;
    return (u16)r;
}
__device__ __forceinline__ float bf_to_f(u16 h) {
    return __uint_as_float(((unsigned)h) << 16);
}

// ---------------- init: deg=1 (self loop), cursor=0, stats=0 ----------------
__global__ void init_kernel(int* __restrict__ deg, int* __restrict__ cursor,
                            float* __restrict__ stats) {
    int i = blockIdx.x * 256 + threadIdx.x;
    if (i < N_NODES) { deg[i] = 1; cursor[i] = 0; }
    if (i < N_LAYERS * 2 * NHID) stats[i] = 0.f;
}

__global__ void deg_count(const int* __restrict__ col, int* __restrict__ deg) {
    int e = blockIdx.x * 256 + threadIdx.x;
    if (e < N_EDGES) atomicAdd(&deg[col[e]], 1);
}

__global__ void dinv_kernel(const int* __restrict__ deg, float* __restrict__ dinv) {
    int i = blockIdx.x * 256 + threadIdx.x;
    if (i < N_NODES) dinv[i] = rsqrtf((float)deg[i]);
}

// ---------------- single-block exclusive scan of (deg-1) -> offs[N+1] ----------------
__global__ void scan_kernel(const int* __restrict__ deg, int* __restrict__ offs) {
    __shared__ int sm[256];
    __shared__ int carry_s;
    int tid = threadIdx.x;
    if (tid == 0) carry_s = 0;
    __syncthreads();
    for (int base = 0; base < N_NODES; base += 256) {
        int i = base + tid;
        int cnt = (i < N_NODES) ? (deg[i] - 1) : 0;
        sm[tid] = cnt;
        __syncthreads();
        #pragma unroll
        for (int off = 1; off < 256; off <<= 1) {
            int v = (tid >= off) ? sm[tid - off] : 0;
            __syncthreads();
            sm[tid] += v;
            __syncthreads();
        }
        int excl = sm[tid] - cnt;
        int carry = carry_s;
        if (i < N_NODES) offs[i] = carry + excl;
        int total = sm[255];
        __syncthreads();
        if (tid == 0) carry_s = carry + total;
        __syncthreads();
    }
    if (tid == 0) offs[N_NODES] = carry_s;
}

__global__ void scatter_kernel(const int* __restrict__ row, const int* __restrict__ col,
                               const float* __restrict__ dinv, const int* __restrict__ offs,
                               int* __restrict__ cursor, int2* __restrict__ csr) {
    int e = blockIdx.x * 256 + threadIdx.x;
    if (e >= N_EDGES) return;
    int c = col[e], r = row[e];
    int pos = offs[c] + atomicAdd(&cursor[c], 1);
    float w = dinv[r] * dinv[c];
    csr[pos] = make_int2(r, __float_as_int(w));
}

// ---------------- split conversions ----------------
__global__ void convert_x(const float4* __restrict__ x4, ushort4* __restrict__ xh,
                          ushort4* __restrict__ xl) {
    int i = blockIdx.x * 256 + threadIdx.x;
    if (i >= N_NODES * NFEAT / 4) return;
    float4 v = x4[i];
    ushort4 h, l;
    h.x = bf_hi_bits(v.x); l.x = bf_hi_bits(v.x - bf_to_f(h.x));
    h.y = bf_hi_bits(v.y); l.y = bf_hi_bits(v.y - bf_to_f(h.y));
    h.z = bf_hi_bits(v.z); l.z = bf_hi_bits(v.z - bf_to_f(h.z));
    h.w = bf_hi_bits(v.w); l.w = bf_hi_bits(v.w - bf_to_f(h.w));
    xh[i] = h; xl[i] = l;
}

// conv_w [8][256][256] -> transposed per-layer [8][n][k]; lin0_w [512][256] -> [256][512]
__global__ void convert_w(const float* __restrict__ cw, u16* __restrict__ wh, u16* __restrict__ wl,
                          const float* __restrict__ l0w, u16* __restrict__ w0h, u16* __restrict__ w0l) {
    int i = blockIdx.x * 256 + threadIdx.x;
    if (i < N_LAYERS * NHID * NHID) {
        int l = i >> 16, rem = i & 65535, n = rem & 255;   // k = rem >> 8
        float f = cw[i];
        u16 h = bf_hi_bits(f); u16 lo = bf_hi_bits(f - bf_to_f(h));
        int o = (l << 16) | (n << 8) | (rem >> 8);
        wh[o] = h; wl[o] = lo;
    } else {
        int j = i - N_LAYERS * NHID * NHID;
        if (j < NFEAT * NHID) {
            int k = j >> 8, n = j & 255;
            float f = l0w[j];
            u16 h = bf_hi_bits(f); u16 lo = bf_hi_bits(f - bf_to_f(h));
            int o = n * NFEAT + k;
            w0h[o] = h; w0l[o] = lo;
        }
    }
}

// ---------------- SpMM + blend, emitting p as bf16 hi/lo split ----------------
__global__ __launch_bounds__(256)
void spmm_blend(const float4* __restrict__ h4, const float4* __restrict__ x04,
                const int* __restrict__ offs, const int2* __restrict__ csr,
                const float* __restrict__ dinv,
                ushort4* __restrict__ ph, ushort4* __restrict__ pl) {
    int wid = threadIdx.x >> 6;
    int lane = threadIdx.x & 63;
    int v = blockIdx.x * 4 + wid;
    if (v >= N_NODES) return;
    float dv = dinv[v];
    float sw = dv * dv;
    float4 acc = h4[(size_t)v * 64 + lane];
    acc.x *= sw; acc.y *= sw; acc.z *= sw; acc.w *= sw;
    int beg = offs[v], end = offs[v + 1];
    for (int e = beg; e < end; ++e) {
        int2 sv = csr[e];
        float w = __int_as_float(sv.y);
        float4 hv = h4[(size_t)sv.x * 64 + lane];
        acc.x = fmaf(w, hv.x, acc.x);
        acc.y = fmaf(w, hv.y, acc.y);
        acc.z = fmaf(w, hv.z, acc.z);
        acc.w = fmaf(w, hv.w, acc.w);
    }
    float4 xv = x04[(size_t)v * 64 + lane];
    float4 r;
    r.x = 0.9f * acc.x + 0.1f * xv.x;
    r.y = 0.9f * acc.y + 0.1f * xv.y;
    r.z = 0.9f * acc.z + 0.1f * xv.z;
    r.w = 0.9f * acc.w + 0.1f * xv.w;
    ushort4 hh, ll;
    hh.x = bf_hi_bits(r.x); ll.x = bf_hi_bits(r.x - bf_to_f(hh.x));
    hh.y = bf_hi_bits(r.y); ll.y = bf_hi_bits(r.y - bf_to_f(hh.y));
    hh.z = bf_hi_bits(r.z); ll.z = bf_hi_bits(r.z - bf_to_f(hh.z));
    hh.w = bf_hi_bits(r.w); ll.w = bf_hi_bits(r.w - bf_to_f(hh.w));
    ph[(size_t)v * 64 + lane] = hh;
    pl[(size_t)v * 64 + lane] = ll;
}

// ---------------- split-bf16 MFMA GEMM ----------------
// C[M][256] = f(A @ B), A = Ah+Al [M][K] bf16-split, B given TRANSPOSED [256][K].
// MODE 0: out = relu(acc + bias)       (lin0)
// MODE 1: out = alpha*acc + rcoef*(Ah+Al at [r][c]); fused BN column sums into stats
// Tile: 64 (M) x 128 (N), 4 waves 2x2, K-step 32, 16x16x32 bf16 MFMA, 3-term split product.
template<int MODE>
__global__ __launch_bounds__(256)
void gemm_mfma(const u16* __restrict__ Ah, const u16* __restrict__ Al,
               const u16* __restrict__ BTh, const u16* __restrict__ BTl,
               const float* __restrict__ bias, float* __restrict__ C,
               float* __restrict__ stats, int M, int K,
               float alpha, float rcoef) {
    __shared__ u16 As_h[64][40], As_l[64][40];     // [m][k] rows padded to 80B
    __shared__ u16 Bs_h[128][40], Bs_l[128][40];   // [n][k]
    int tid = threadIdx.x;
    int lane = tid & 63, wid = tid >> 6;
    int wr = wid >> 1, wc = wid & 1;
    int brow = blockIdx.x * 64;
    int bcol = blockIdx.y * 128;

    f32x4 acc[2][4];
    #pragma unroll
    for (int i = 0; i < 2; ++i)
        #pragma unroll
        for (int j = 0; j < 4; ++j) { acc[i][j].x = 0.f; acc[i][j].y = 0.f; acc[i][j].z = 0.f; acc[i][j].w = 0.f; }

    int am = tid >> 2, akc = (tid & 3) * 8;        // A: 64 rows x 4 chunks of 8
    int bn = tid >> 1, bkc = (tid & 1) * 16;       // B: 128 rows x 2x(2 chunks of 8)
    bool aval = (brow + am) < M;
    size_t arow_off = (size_t)(brow + am) * K + akc;
    size_t brow_off = (size_t)(bcol + bn) * K + bkc;
    int rlo = lane & 15, kg = (lane >> 4) * 8;

    for (int k0 = 0; k0 < K; k0 += 32) {
        uint4 z4 = make_uint4(0, 0, 0, 0);
        uint4 a_h = aval ? *(const uint4*)(Ah + arow_off + k0) : z4;
        uint4 a_l = aval ? *(const uint4*)(Al + arow_off + k0) : z4;
        uint4 b_h0 = *(const uint4*)(BTh + brow_off + k0);
        uint4 b_h1 = *(const uint4*)(BTh + brow_off + k0 + 8);
        uint4 b_l0 = *(const uint4*)(BTl + brow_off + k0);
        uint4 b_l1 = *(const uint4*)(BTl + brow_off + k0 + 8);
        __syncthreads();   // prior iter's fragment reads done before overwrite
        *(uint4*)&As_h[am][akc] = a_h;
        *(uint4*)&As_l[am][akc] = a_l;
        *(uint4*)&Bs_h[bn][bkc] = b_h0;
        *(uint4*)&Bs_h[bn][bkc + 8] = b_h1;
        *(uint4*)&Bs_l[bn][bkc] = b_l0;
        *(uint4*)&Bs_l[bn][bkc + 8] = b_l1;
        __syncthreads();

        short8v afh[2], afl[2], bfh[4], bfl[4];
        #pragma unroll
        for (int mf = 0; mf < 2; ++mf) {
            afh[mf] = *(const short8v*)&As_h[wr * 32 + mf * 16 + rlo][kg];
            afl[mf] = *(const short8v*)&As_l[wr * 32 + mf * 16 + rlo][kg];
        }
        #pragma unroll
        for (int nf = 0; nf < 4; ++nf) {
            bfh[nf] = *(const short8v*)&Bs_h[wc * 64 + nf * 16 + rlo][kg];
            bfl[nf] = *(const short8v*)&Bs_l[wc * 64 + nf * 16 + rlo][kg];
        }
        #pragma unroll
        for (int mf = 0; mf < 2; ++mf)
            #pragma unroll
            for (int nf = 0; nf < 4; ++nf) {
                acc[mf][nf] = __builtin_amdgcn_mfma_f32_16x16x32_bf16(afl[mf], bfh[nf], acc[mf][nf], 0, 0, 0);
                acc[mf][nf] = __builtin_amdgcn_mfma_f32_16x16x32_bf16(afh[mf], bfl[nf], acc[mf][nf], 0, 0, 0);
                acc[mf][nf] = __builtin_amdgcn_mfma_f32_16x16x32_bf16(afh[mf], bfh[nf], acc[mf][nf], 0, 0, 0);
            }
    }

    // epilogue: D layout col=lane&15, row=(lane>>4)*4+reg  [m89-verified]
    int r0 = brow + wr * 32 + (lane >> 4) * 4;
    #pragma unroll
    for (int nf = 0; nf < 4; ++nf) {
        int c = bcol + wc * 64 + nf * 16 + rlo;
        float s = 0.f, s2 = 0.f;
        float bv = (MODE == 0) ? bias[c] : 0.f;
        #pragma unroll
        for (int mf = 0; mf < 2; ++mf) {
            #pragma unroll
            for (int reg = 0; reg < 4; ++reg) {
                int rr = r0 + mf * 16 + reg;
                if (rr < M) {
                    float o;
                    if (MODE == 0) {
                        o = fmaxf(acc[mf][nf][reg] + bv, 0.f);
                    } else {
                        size_t pi = (size_t)rr * K + c;   // K == NHID in conv mode
                        float p = bf_to_f(Ah[pi]) + bf_to_f(Al[pi]);
                        o = alpha * acc[mf][nf][reg] + rcoef * p;
                        s += o; s2 = fmaf(o, o, s2);
                    }
                    C[(size_t)rr * NHID + c] = o;
                }
            }
        }
        if (MODE == 1) {
            s  += __shfl_xor(s, 16);  s  += __shfl_xor(s, 32);
            s2 += __shfl_xor(s2, 16); s2 += __shfl_xor(s2, 32);
            if (lane < 16) {
                atomicAdd(&stats[c], s);
                atomicAdd(&stats[NHID + c], s2);
            }
        }
    }
}

// ---------------- fp32 GEMM kept for lin1 (N=64) ----------------
template<bool BIAS, bool RELU>
__global__ __launch_bounds__(256)
void gemm64(const float* __restrict__ A, const float* __restrict__ B,
            const float* __restrict__ bias, float* __restrict__ C,
            int M, int Nc, int K) {
    __shared__ float As[16][68];
    __shared__ float Bs[16][68];
    int tid = threadIdx.x;
    int tc = tid & 15, tr = tid >> 4;
    int brow = blockIdx.x * 64, bcol = blockIdx.y * 64;
    float acc[4][4] = {};
    int arow = tid >> 2;
    int ak = (tid & 3) * 4;
    int bkrow = tid >> 4;
    int bcol4 = (tid & 15) * 4;

    for (int k0 = 0; k0 < K; k0 += 16) {
        int gr = brow + arow;
        float4 av = (gr < M) ? *(const float4*)&A[(size_t)gr * K + k0 + ak]
                             : make_float4(0.f, 0.f, 0.f, 0.f);
        As[ak + 0][arow] = av.x;
        As[ak + 1][arow] = av.y;
        As[ak + 2][arow] = av.z;
        As[ak + 3][arow] = av.w;
        float4 bv = *(const float4*)&B[(size_t)(k0 + bkrow) * Nc + bcol + bcol4];
        *(float4*)&Bs[bkrow][bcol4] = bv;
        __syncthreads();
        #pragma unroll
        for (int kk = 0; kk < 16; ++kk) {
            float4 a = *(const float4*)&As[kk][tr * 4];
            float4 b = *(const float4*)&Bs[kk][tc * 4];
            acc[0][0] = fmaf(a.x, b.x, acc[0][0]);
            acc[0][1] = fmaf(a.x, b.y, acc[0][1]);
            acc[0][2] = fmaf(a.x, b.z, acc[0][2]);
            acc[0][3] = fmaf(a.x, b.w, acc[0][3]);
            acc[1][0] = fmaf(a.y, b.x, acc[1][0]);
            acc[1][1] = fmaf(a.y, b.y, acc[1][1]);
            acc[1][2] = fmaf(a.y, b.z, acc[1][2]);
            acc[1][3] = fmaf(a.y, b.w, acc[1][3]);
            acc[2][0] = fmaf(a.z, b.x, acc[2][0]);
            acc[2][1] = fmaf(a.z, b.y, acc[2][1]);
            acc[2][2] = fmaf(a.z, b.z, acc[2][2]);
            acc[2][3] = fmaf(a.z, b.w, acc[2][3]);
            acc[3][0] = fmaf(a.w, b.x, acc[3][0]);
            acc[3][1] = fmaf(a.w, b.y, acc[3][1]);
            acc[3][2] = fmaf(a.w, b.z, acc[3][2]);
            acc[3][3] = fmaf(a.w, b.w, acc[3][3]);
        }
        __syncthreads();
    }

    int r0 = brow + tr * 4, c0 = bcol + tc * 4;
    float4 b4 = make_float4(0.f, 0.f, 0.f, 0.f);
    if (BIAS) b4 = *(const float4*)&bias[c0];
    #pragma unroll
    for (int i = 0; i < 4; ++i) {
        int r = r0 + i;
        if (r >= M) continue;
        float4 o;
        o.x = acc[i][0] + b4.x;
        o.y = acc[i][1] + b4.y;
        o.z = acc[i][2] + b4.z;
        o.w = acc[i][3] + b4.w;
        if (RELU) {
            o.x = fmaxf(o.x, 0.f); o.y = fmaxf(o.y, 0.f);
            o.z = fmaxf(o.z, 0.f); o.w = fmaxf(o.w, 0.f);
        }
        *(float4*)&C[(size_t)r * Nc + c0] = o;
    }
}

// ---------------- BN finalize + apply ----------------
__global__ void bn_final(const float* __restrict__ stats, const float* __restrict__ g,
                         const float* __restrict__ b, float* __restrict__ AB) {
    int f = threadIdx.x;
    float mu = stats[f] * (1.f / N_NODES);
    float var = stats[NHID + f] * (1.f / N_NODES) - mu * mu;
    float rs = rsqrtf(var + BN_EPS);
    float a = g[f] * rs;
    AB[f] = a;
    AB[NHID + f] = b[f] - mu * a;
}

__global__ __launch_bounds__(256)
void bn_apply(const float4* __restrict__ out4, const float* __restrict__ AB,
              float4* __restrict__ h4) {
    int i = blockIdx.x * 256 + threadIdx.x;
    if (i >= N_NODES * 64) return;
    int f4 = (i & 63) * 4;
    float4 v = out4[i];
    float4 r;
    r.x = fmaxf(fmaf(v.x, AB[f4 + 0], AB[NHID + f4 + 0]), 0.f);
    r.y = fmaxf(fmaf(v.y, AB[f4 + 1], AB[NHID + f4 + 1]), 0.f);
    r.z = fmaxf(fmaf(v.z, AB[f4 + 2], AB[NHID + f4 + 2]), 0.f);
    r.w = fmaxf(fmaf(v.w, AB[f4 + 3], AB[NHID + f4 + 3]), 0.f);
    h4[i] = r;
}

// ---------------- host ----------------
static inline size_t align_up(size_t x, size_t a) { return (x + a - 1) & ~(a - 1); }

extern "C" void kernel_launch(void* const* d_in, const int* in_sizes, int n_in,
                              void* d_out, int out_size, void* d_ws, size_t ws_size,
                              hipStream_t stream) {
    const float* x       = (const float*)d_in[0];
    const int*   ei      = (const int*)d_in[1];
    const float* lin0_w  = (const float*)d_in[2];
    const float* lin0_b  = (const float*)d_in[3];
    const float* lin1_w  = (const float*)d_in[4];
    const float* lin1_b  = (const float*)d_in[5];
    const float* conv_w  = (const float*)d_in[6];
    const float* bn_g    = (const float*)d_in[7];
    const float* bn_b    = (const float*)d_in[8];
    const int* rowp = ei;
    const int* colp = ei + N_EDGES;
    float* outp = (float*)d_out;

    char* ws = (char*)d_ws;
    size_t off = 0;
    auto alloc = [&](size_t bytes) { size_t o = off; off = align_up(off + bytes, 256); return ws + o; };
    int*   deg    = (int*)alloc(N_NODES * 4);
    int*   cursor = (int*)alloc(N_NODES * 4);
    int*   offs   = (int*)alloc((N_NODES + 1) * 4);
    float* dinv   = (float*)alloc(N_NODES * 4);
    int2*  csr    = (int2*)alloc((size_t)N_EDGES * 8);
    float* x0     = (float*)alloc((size_t)N_NODES * NHID * 4);
    float* h      = (float*)alloc((size_t)N_NODES * NHID * 4);
    float* outb   = (float*)alloc((size_t)N_NODES * NHID * 4);
    float* stats  = (float*)alloc(N_LAYERS * 2 * NHID * 4);
    float* AB     = (float*)alloc(2 * NHID * 4);
    u16*   xh     = (u16*)alloc((size_t)N_NODES * NFEAT * 2);  // reused as p_hi after lin0
    u16*   xl     = (u16*)alloc((size_t)N_NODES * NFEAT * 2);  // reused as p_lo after lin0
    u16*   wh     = (u16*)alloc((size_t)N_LAYERS * NHID * NHID * 2);
    u16*   wl     = (u16*)alloc((size_t)N_LAYERS * NHID * NHID * 2);
    u16*   w0h    = (u16*)alloc((size_t)NFEAT * NHID * 2);
    u16*   w0l    = (u16*)alloc((size_t)NFEAT * NHID * 2);
    (void)ws_size; (void)n_in; (void)in_sizes; (void)out_size;

    // graph preprocessing
    init_kernel<<<40, 256, 0, stream>>>(deg, cursor, stats);
    deg_count<<<(N_EDGES + 255) / 256, 256, 0, stream>>>(colp, deg);
    dinv_kernel<<<(N_NODES + 255) / 256, 256, 0, stream>>>(deg, dinv);
    scan_kernel<<<1, 256, 0, stream>>>(deg, offs);
    scatter_kernel<<<(N_EDGES + 255) / 256, 256, 0, stream>>>(rowp, colp, dinv, offs, cursor, csr);

    // weight + input splits
    convert_w<<<(N_LAYERS * NHID * NHID + NFEAT * NHID + 255) / 256, 256, 0, stream>>>(
        conv_w, wh, wl, lin0_w, w0h, w0l);
    convert_x<<<(N_NODES * NFEAT / 4 + 255) / 256, 256, 0, stream>>>(
        (const float4*)x, (ushort4*)xh, (ushort4*)xl);

    // lin0: x0 = relu(x @ W0 + b0)   [MFMA split-bf16]
    gemm_mfma<0><<<dim3(157, 2), 256, 0, stream>>>(
        xh, xl, w0h, w0l, lin0_b, x0, nullptr, N_NODES, NFEAT, 1.f, 0.f);

    u16* ph = xh;  // alias: x splits no longer needed
    u16* pl = xl;

    const float* h_in = x0;
    for (int l = 0; l < N_LAYERS; ++l) {
        float beta = logf(0.5f / (float)(l + 1) + 1.0f);
        spmm_blend<<<2500, 256, 0, stream>>>(
            (const float4*)h_in, (const float4*)x0, offs, csr, dinv,
            (ushort4*)ph, (ushort4*)pl);
        gemm_mfma<1><<<dim3(157, 2), 256, 0, stream>>>(
            ph, pl, wh + (size_t)l * NHID * NHID, wl + (size_t)l * NHID * NHID,
            nullptr, outb, stats + l * 2 * NHID, N_NODES, NHID, beta, 1.f - beta);
        bn_final<<<1, 256, 0, stream>>>(stats + l * 2 * NHID, bn_g + l * NHID, bn_b + l * NHID, AB);
        bn_apply<<<2500, 256, 0, stream>>>((const float4*)outb, AB, (float4*)h);
        h_in = h;
    }

    // lin1: out = h @ W1 + b1
    gemm64<true, false><<<dim3(157, 1), 256, 0, stream>>>(
        h, lin1_w, lin1_b, outp, N_NODES, NCLASS, NHID);
}

// Round 5
// 729.598 us; speedup vs baseline: 1.5467x; 1.1939x over previous
//
#include <hip/hip_runtime.h>
#include <hip/hip_fp16.h>
#include <math.h>

#define N_NODES 10000
#define N_EDGES 320000
#define NFEAT 512
#define NHID 256
#define NCLASS 64
#define N_LAYERS 8
#define BN_EPS 1e-5f

typedef unsigned short u16;
typedef __attribute__((ext_vector_type(8))) short short8v;
typedef __attribute__((ext_vector_type(4))) float f32x4;

__device__ __forceinline__ u16 bf_hi_bits(float f) {
    unsigned u = __float_as_uint(f);
    unsigned r = (u + 0x7fffu + ((u >> 16) & 1u)) >> 16;
    return (u16)r;
}
__device__ __forceinline__ float bf_to_f(u16 h) {
    return __uint_as_float(((unsigned)h) << 16);
}
// load 4 consecutive fp16 as float4 (8B load)
__device__ __forceinline__ float4 loadh4(const __half* p) {
    float2 raw = *(const float2*)p;
    __half2 h0 = *reinterpret_cast<const __half2*>(&raw.x);
    __half2 h1 = *reinterpret_cast<const __half2*>(&raw.y);
    float2 f0 = __half22float2(h0);
    float2 f1 = __half22float2(h1);
    return make_float4(f0.x, f0.y, f1.x, f1.y);
}
// store float4 as 4 fp16 (8B store)
__device__ __forceinline__ void storeh4(__half* p, float4 v) {
    __half2 h0 = __float22half2_rn(make_float2(v.x, v.y));
    __half2 h1 = __float22half2_rn(make_float2(v.z, v.w));
    float2 raw;
    raw.x = *reinterpret_cast<float*>(&h0);
    raw.y = *reinterpret_cast<float*>(&h1);
    *(float2*)p = raw;
}

// ---------------- init: deg=1 (self loop), cursor=0, stats=0 ----------------
__global__ void init_kernel(int* __restrict__ deg, int* __restrict__ cursor,
                            float* __restrict__ stats) {
    int i = blockIdx.x * 256 + threadIdx.x;
    if (i < N_NODES) { deg[i] = 1; cursor[i] = 0; }
    if (i < N_LAYERS * 2 * NHID) stats[i] = 0.f;
}

__global__ void deg_count(const int* __restrict__ col, int* __restrict__ deg) {
    int e = blockIdx.x * 256 + threadIdx.x;
    if (e < N_EDGES) atomicAdd(&deg[col[e]], 1);
}

__global__ void dinv_kernel(const int* __restrict__ deg, float* __restrict__ dinv) {
    int i = blockIdx.x * 256 + threadIdx.x;
    if (i < N_NODES) dinv[i] = rsqrtf((float)deg[i]);
}

// ---------------- single-block exclusive scan of (deg-1) -> offs[N+1] ----------------
__global__ void scan_kernel(const int* __restrict__ deg, int* __restrict__ offs) {
    __shared__ int sm[256];
    __shared__ int carry_s;
    int tid = threadIdx.x;
    if (tid == 0) carry_s = 0;
    __syncthreads();
    for (int base = 0; base < N_NODES; base += 256) {
        int i = base + tid;
        int cnt = (i < N_NODES) ? (deg[i] - 1) : 0;
        sm[tid] = cnt;
        __syncthreads();
        #pragma unroll
        for (int off = 1; off < 256; off <<= 1) {
            int v = (tid >= off) ? sm[tid - off] : 0;
            __syncthreads();
            sm[tid] += v;
            __syncthreads();
        }
        int excl = sm[tid] - cnt;
        int carry = carry_s;
        if (i < N_NODES) offs[i] = carry + excl;
        int total = sm[255];
        __syncthreads();
        if (tid == 0) carry_s = carry + total;
        __syncthreads();
    }
    if (tid == 0) offs[N_NODES] = carry_s;
}

__global__ void scatter_kernel(const int* __restrict__ row, const int* __restrict__ col,
                               const float* __restrict__ dinv, const int* __restrict__ offs,
                               int* __restrict__ cursor, int2* __restrict__ csr) {
    int e = blockIdx.x * 256 + threadIdx.x;
    if (e >= N_EDGES) return;
    int c = col[e], r = row[e];
    int pos = offs[c] + atomicAdd(&cursor[c], 1);
    float w = dinv[r] * dinv[c];
    csr[pos] = make_int2(r, __float_as_int(w));
}

// ---------------- split conversions ----------------
__global__ void convert_x(const float4* __restrict__ x4, ushort4* __restrict__ xh,
                          ushort4* __restrict__ xl) {
    int i = blockIdx.x * 256 + threadIdx.x;
    if (i >= N_NODES * NFEAT / 4) return;
    float4 v = x4[i];
    ushort4 h, l;
    h.x = bf_hi_bits(v.x); l.x = bf_hi_bits(v.x - bf_to_f(h.x));
    h.y = bf_hi_bits(v.y); l.y = bf_hi_bits(v.y - bf_to_f(h.y));
    h.z = bf_hi_bits(v.z); l.z = bf_hi_bits(v.z - bf_to_f(h.z));
    h.w = bf_hi_bits(v.w); l.w = bf_hi_bits(v.w - bf_to_f(h.w));
    xh[i] = h; xl[i] = l;
}

// conv_w [8][256][256] -> transposed per-layer [8][n][k]; lin0_w [512][256] -> [256][512]
__global__ void convert_w(const float* __restrict__ cw, u16* __restrict__ wh, u16* __restrict__ wl,
                          const float* __restrict__ l0w, u16* __restrict__ w0h, u16* __restrict__ w0l) {
    int i = blockIdx.x * 256 + threadIdx.x;
    if (i < N_LAYERS * NHID * NHID) {
        int l = i >> 16, rem = i & 65535, n = rem & 255;   // k = rem >> 8
        float f = cw[i];
        u16 h = bf_hi_bits(f); u16 lo = bf_hi_bits(f - bf_to_f(h));
        int o = (l << 16) | (n << 8) | (rem >> 8);
        wh[o] = h; wl[o] = lo;
    } else {
        int j = i - N_LAYERS * NHID * NHID;
        if (j < NFEAT * NHID) {
            int k = j >> 8, n = j & 255;
            float f = l0w[j];
            u16 h = bf_hi_bits(f); u16 lo = bf_hi_bits(f - bf_to_f(h));
            int o = n * NFEAT + k;
            w0h[o] = h; w0l[o] = lo;
        }
    }
}

// ---------------- SpMM + blend (fp16 gathers), emitting p as bf16 hi/lo split ----------------
// one wave per node; 64 lanes x 4 fp16 feats = 256; 2-edge unroll, dual accumulators
__global__ __launch_bounds__(256)
void spmm_blend(const __half* __restrict__ hb, const __half* __restrict__ x0b,
                const int* __restrict__ offs, const int2* __restrict__ csr,
                const float* __restrict__ dinv,
                ushort4* __restrict__ ph, ushort4* __restrict__ pl) {
    int wid = threadIdx.x >> 6;
    int lane = threadIdx.x & 63;
    int v = blockIdx.x * 4 + wid;
    if (v >= N_NODES) return;
    int f0 = lane * 4;
    size_t base = (size_t)v * NHID + f0;
    float dv = dinv[v];
    float sw = dv * dv;
    float4 a0 = loadh4(hb + base);          // self loop
    a0.x *= sw; a0.y *= sw; a0.z *= sw; a0.w *= sw;
    float4 a1 = make_float4(0.f, 0.f, 0.f, 0.f);
    int beg = offs[v], end = offs[v + 1];
    int e = beg;
    for (; e + 1 < end; e += 2) {
        int2 s0 = csr[e];
        int2 s1 = csr[e + 1];
        float w0 = __int_as_float(s0.y);
        float w1 = __int_as_float(s1.y);
        float4 h0 = loadh4(hb + (size_t)s0.x * NHID + f0);
        float4 h1 = loadh4(hb + (size_t)s1.x * NHID + f0);
        a0.x = fmaf(w0, h0.x, a0.x); a1.x = fmaf(w1, h1.x, a1.x);
        a0.y = fmaf(w0, h0.y, a0.y); a1.y = fmaf(w1, h1.y, a1.y);
        a0.z = fmaf(w0, h0.z, a0.z); a1.z = fmaf(w1, h1.z, a1.z);
        a0.w = fmaf(w0, h0.w, a0.w); a1.w = fmaf(w1, h1.w, a1.w);
    }
    if (e < end) {
        int2 s0 = csr[e];
        float w0 = __int_as_float(s0.y);
        float4 h0 = loadh4(hb + (size_t)s0.x * NHID + f0);
        a0.x = fmaf(w0, h0.x, a0.x);
        a0.y = fmaf(w0, h0.y, a0.y);
        a0.z = fmaf(w0, h0.z, a0.z);
        a0.w = fmaf(w0, h0.w, a0.w);
    }
    float4 xv = loadh4(x0b + base);
    float4 r;
    r.x = 0.9f * (a0.x + a1.x) + 0.1f * xv.x;
    r.y = 0.9f * (a0.y + a1.y) + 0.1f * xv.y;
    r.z = 0.9f * (a0.z + a1.z) + 0.1f * xv.z;
    r.w = 0.9f * (a0.w + a1.w) + 0.1f * xv.w;
    ushort4 hh, ll;
    hh.x = bf_hi_bits(r.x); ll.x = bf_hi_bits(r.x - bf_to_f(hh.x));
    hh.y = bf_hi_bits(r.y); ll.y = bf_hi_bits(r.y - bf_to_f(hh.y));
    hh.z = bf_hi_bits(r.z); ll.z = bf_hi_bits(r.z - bf_to_f(hh.z));
    hh.w = bf_hi_bits(r.w); ll.w = bf_hi_bits(r.w - bf_to_f(hh.w));
    ph[(size_t)v * 64 + lane] = hh;
    pl[(size_t)v * 64 + lane] = ll;
}

// ---------------- split-bf16 MFMA GEMM ----------------
// C(fp16)[M][256] = f(A @ B), A = Ah+Al [M][K] bf16-split, B TRANSPOSED [256][K].
// MODE 0: out = relu(acc + bias)       (lin0 -> x0 fp16)
// MODE 1: out = alpha*acc + rcoef*(Ah+Al); fused BN column sums (fp32, pre-rounding)
template<int MODE>
__global__ __launch_bounds__(256)
void gemm_mfma(const u16* __restrict__ Ah, const u16* __restrict__ Al,
               const u16* __restrict__ BTh, const u16* __restrict__ BTl,
               const float* __restrict__ bias, __half* __restrict__ C,
               float* __restrict__ stats, int M, int K,
               float alpha, float rcoef) {
    __shared__ u16 As_h[64][40], As_l[64][40];
    __shared__ u16 Bs_h[128][40], Bs_l[128][40];
    int tid = threadIdx.x;
    int lane = tid & 63, wid = tid >> 6;
    int wr = wid >> 1, wc = wid & 1;
    int brow = blockIdx.x * 64;
    int bcol = blockIdx.y * 128;

    f32x4 acc[2][4];
    #pragma unroll
    for (int i = 0; i < 2; ++i)
        #pragma unroll
        for (int j = 0; j < 4; ++j) { acc[i][j].x = 0.f; acc[i][j].y = 0.f; acc[i][j].z = 0.f; acc[i][j].w = 0.f; }

    int am = tid >> 2, akc = (tid & 3) * 8;
    int bn = tid >> 1, bkc = (tid & 1) * 16;
    bool aval = (brow + am) < M;
    size_t arow_off = (size_t)(brow + am) * K + akc;
    size_t brow_off = (size_t)(bcol + bn) * K + bkc;
    int rlo = lane & 15, kg = (lane >> 4) * 8;

    for (int k0 = 0; k0 < K; k0 += 32) {
        uint4 z4 = make_uint4(0, 0, 0, 0);
        uint4 a_h = aval ? *(const uint4*)(Ah + arow_off + k0) : z4;
        uint4 a_l = aval ? *(const uint4*)(Al + arow_off + k0) : z4;
        uint4 b_h0 = *(const uint4*)(BTh + brow_off + k0);
        uint4 b_h1 = *(const uint4*)(BTh + brow_off + k0 + 8);
        uint4 b_l0 = *(const uint4*)(BTl + brow_off + k0);
        uint4 b_l1 = *(const uint4*)(BTl + brow_off + k0 + 8);
        __syncthreads();
        *(uint4*)&As_h[am][akc] = a_h;
        *(uint4*)&As_l[am][akc] = a_l;
        *(uint4*)&Bs_h[bn][bkc] = b_h0;
        *(uint4*)&Bs_h[bn][bkc + 8] = b_h1;
        *(uint4*)&Bs_l[bn][bkc] = b_l0;
        *(uint4*)&Bs_l[bn][bkc + 8] = b_l1;
        __syncthreads();

        short8v afh[2], afl[2], bfh[4], bfl[4];
        #pragma unroll
        for (int mf = 0; mf < 2; ++mf) {
            afh[mf] = *(const short8v*)&As_h[wr * 32 + mf * 16 + rlo][kg];
            afl[mf] = *(const short8v*)&As_l[wr * 32 + mf * 16 + rlo][kg];
        }
        #pragma unroll
        for (int nf = 0; nf < 4; ++nf) {
            bfh[nf] = *(const short8v*)&Bs_h[wc * 64 + nf * 16 + rlo][kg];
            bfl[nf] = *(const short8v*)&Bs_l[wc * 64 + nf * 16 + rlo][kg];
        }
        #pragma unroll
        for (int mf = 0; mf < 2; ++mf)
            #pragma unroll
            for (int nf = 0; nf < 4; ++nf) {
                acc[mf][nf] = __builtin_amdgcn_mfma_f32_16x16x32_bf16(afl[mf], bfh[nf], acc[mf][nf], 0, 0, 0);
                acc[mf][nf] = __builtin_amdgcn_mfma_f32_16x16x32_bf16(afh[mf], bfl[nf], acc[mf][nf], 0, 0, 0);
                acc[mf][nf] = __builtin_amdgcn_mfma_f32_16x16x32_bf16(afh[mf], bfh[nf], acc[mf][nf], 0, 0, 0);
            }
    }

    // epilogue: D layout col=lane&15, row=(lane>>4)*4+reg  [m89-verified]
    int r0 = brow + wr * 32 + (lane >> 4) * 4;
    #pragma unroll
    for (int nf = 0; nf < 4; ++nf) {
        int c = bcol + wc * 64 + nf * 16 + rlo;
        float s = 0.f, s2 = 0.f;
        float bv = (MODE == 0) ? bias[c] : 0.f;
        #pragma unroll
        for (int mf = 0; mf < 2; ++mf) {
            #pragma unroll
            for (int reg = 0; reg < 4; ++reg) {
                int rr = r0 + mf * 16 + reg;
                if (rr < M) {
                    float o;
                    if (MODE == 0) {
                        o = fmaxf(acc[mf][nf][reg] + bv, 0.f);
                    } else {
                        size_t pi = (size_t)rr * K + c;   // K == NHID in conv mode
                        float p = bf_to_f(Ah[pi]) + bf_to_f(Al[pi]);
                        o = alpha * acc[mf][nf][reg] + rcoef * p;
                        s += o; s2 = fmaf(o, o, s2);
                    }
                    C[(size_t)rr * NHID + c] = __float2half(o);
                }
            }
        }
        if (MODE == 1) {
            s  += __shfl_xor(s, 16);  s  += __shfl_xor(s, 32);
            s2 += __shfl_xor(s2, 16); s2 += __shfl_xor(s2, 32);
            if (lane < 16) {
                atomicAdd(&stats[c], s);
                atomicAdd(&stats[NHID + c], s2);
            }
        }
    }
}

// ---------------- fp32 GEMM for lin1 (A is fp16) ----------------
__global__ __launch_bounds__(256)
void gemm_lin1(const __half* __restrict__ A, const float* __restrict__ B,
               const float* __restrict__ bias, float* __restrict__ C,
               int M, int Nc, int K) {
    __shared__ float As[16][68];
    __shared__ float Bs[16][68];
    int tid = threadIdx.x;
    int tc = tid & 15, tr = tid >> 4;
    int brow = blockIdx.x * 64, bcol = blockIdx.y * 64;
    float acc[4][4] = {};
    int arow = tid >> 2;
    int ak = (tid & 3) * 4;
    int bkrow = tid >> 4;
    int bcol4 = (tid & 15) * 4;

    for (int k0 = 0; k0 < K; k0 += 16) {
        int gr = brow + arow;
        float4 av = (gr < M) ? loadh4(A + (size_t)gr * K + k0 + ak)
                             : make_float4(0.f, 0.f, 0.f, 0.f);
        As[ak + 0][arow] = av.x;
        As[ak + 1][arow] = av.y;
        As[ak + 2][arow] = av.z;
        As[ak + 3][arow] = av.w;
        float4 bv = *(const float4*)&B[(size_t)(k0 + bkrow) * Nc + bcol + bcol4];
        *(float4*)&Bs[bkrow][bcol4] = bv;
        __syncthreads();
        #pragma unroll
        for (int kk = 0; kk < 16; ++kk) {
            float4 a = *(const float4*)&As[kk][tr * 4];
            float4 b = *(const float4*)&Bs[kk][tc * 4];
            acc[0][0] = fmaf(a.x, b.x, acc[0][0]);
            acc[0][1] = fmaf(a.x, b.y, acc[0][1]);
            acc[0][2] = fmaf(a.x, b.z, acc[0][2]);
            acc[0][3] = fmaf(a.x, b.w, acc[0][3]);
            acc[1][0] = fmaf(a.y, b.x, acc[1][0]);
            acc[1][1] = fmaf(a.y, b.y, acc[1][1]);
            acc[1][2] = fmaf(a.y, b.z, acc[1][2]);
            acc[1][3] = fmaf(a.y, b.w, acc[1][3]);
            acc[2][0] = fmaf(a.z, b.x, acc[2][0]);
            acc[2][1] = fmaf(a.z, b.y, acc[2][1]);
            acc[2][2] = fmaf(a.z, b.z, acc[2][2]);
            acc[2][3] = fmaf(a.z, b.w, acc[2][3]);
            acc[3][0] = fmaf(a.w, b.x, acc[3][0]);
            acc[3][1] = fmaf(a.w, b.y, acc[3][1]);
            acc[3][2] = fmaf(a.w, b.z, acc[3][2]);
            acc[3][3] = fmaf(a.w, b.w, acc[3][3]);
        }
        __syncthreads();
    }

    int r0 = brow + tr * 4, c0 = bcol + tc * 4;
    float4 b4 = *(const float4*)&bias[c0];
    #pragma unroll
    for (int i = 0; i < 4; ++i) {
        int r = r0 + i;
        if (r >= M) continue;
        float4 o;
        o.x = acc[i][0] + b4.x;
        o.y = acc[i][1] + b4.y;
        o.z = acc[i][2] + b4.z;
        o.w = acc[i][3] + b4.w;
        *(float4*)&C[(size_t)r * Nc + c0] = o;
    }
}

// ---------------- BN finalize + apply ----------------
__global__ void bn_final(const float* __restrict__ stats, const float* __restrict__ g,
                         const float* __restrict__ b, float* __restrict__ AB) {
    int f = threadIdx.x;
    float mu = stats[f] * (1.f / N_NODES);
    float var = stats[NHID + f] * (1.f / N_NODES) - mu * mu;
    float rs = rsqrtf(var + BN_EPS);
    float a = g[f] * rs;
    AB[f] = a;
    AB[NHID + f] = b[f] - mu * a;
}

__global__ __launch_bounds__(256)
void bn_apply(const __half* __restrict__ outh, const float* __restrict__ AB,
              __half* __restrict__ hb) {
    int i = blockIdx.x * 256 + threadIdx.x;   // over N_NODES*64 groups of 4
    if (i >= N_NODES * 64) return;
    int f4 = (i & 63) * 4;
    float4 v = loadh4(outh + (size_t)i * 4);
    float4 r;
    r.x = fmaxf(fmaf(v.x, AB[f4 + 0], AB[NHID + f4 + 0]), 0.f);
    r.y = fmaxf(fmaf(v.y, AB[f4 + 1], AB[NHID + f4 + 1]), 0.f);
    r.z = fmaxf(fmaf(v.z, AB[f4 + 2], AB[NHID + f4 + 2]), 0.f);
    r.w = fmaxf(fmaf(v.w, AB[f4 + 3], AB[NHID + f4 + 3]), 0.f);
    storeh4(hb + (size_t)i * 4, r);
}

// ---------------- host ----------------
static inline size_t align_up(size_t x, size_t a) { return (x + a - 1) & ~(a - 1); }

extern "C" void kernel_launch(void* const* d_in, const int* in_sizes, int n_in,
                              void* d_out, int out_size, void* d_ws, size_t ws_size,
                              hipStream_t stream) {
    const float* x       = (const float*)d_in[0];
    const int*   ei      = (const int*)d_in[1];
    const float* lin0_w  = (const float*)d_in[2];
    const float* lin0_b  = (const float*)d_in[3];
    const float* lin1_w  = (const float*)d_in[4];
    const float* lin1_b  = (const float*)d_in[5];
    const float* conv_w  = (const float*)d_in[6];
    const float* bn_g    = (const float*)d_in[7];
    const float* bn_b    = (const float*)d_in[8];
    const int* rowp = ei;
    const int* colp = ei + N_EDGES;
    float* outp = (float*)d_out;

    char* ws = (char*)d_ws;
    size_t off = 0;
    auto alloc = [&](size_t bytes) { size_t o = off; off = align_up(off + bytes, 256); return ws + o; };
    int*    deg    = (int*)alloc(N_NODES * 4);
    int*    cursor = (int*)alloc(N_NODES * 4);
    int*    offs   = (int*)alloc((N_NODES + 1) * 4);
    float*  dinv   = (float*)alloc(N_NODES * 4);
    int2*   csr    = (int2*)alloc((size_t)N_EDGES * 8);
    __half* x0     = (__half*)alloc((size_t)N_NODES * NHID * 2);
    __half* hbuf   = (__half*)alloc((size_t)N_NODES * NHID * 2);
    __half* outb   = (__half*)alloc((size_t)N_NODES * NHID * 2);
    float*  stats  = (float*)alloc(N_LAYERS * 2 * NHID * 4);
    float*  AB     = (float*)alloc(2 * NHID * 4);
    u16*    xh     = (u16*)alloc((size_t)N_NODES * NFEAT * 2);  // reused as p_hi after lin0
    u16*    xl     = (u16*)alloc((size_t)N_NODES * NFEAT * 2);  // reused as p_lo after lin0
    u16*    wh     = (u16*)alloc((size_t)N_LAYERS * NHID * NHID * 2);
    u16*    wl     = (u16*)alloc((size_t)N_LAYERS * NHID * NHID * 2);
    u16*    w0h    = (u16*)alloc((size_t)NFEAT * NHID * 2);
    u16*    w0l    = (u16*)alloc((size_t)NFEAT * NHID * 2);
    (void)ws_size; (void)n_in; (void)in_sizes; (void)out_size;

    // graph preprocessing
    init_kernel<<<40, 256, 0, stream>>>(deg, cursor, stats);
    deg_count<<<(N_EDGES + 255) / 256, 256, 0, stream>>>(colp, deg);
    dinv_kernel<<<(N_NODES + 255) / 256, 256, 0, stream>>>(deg, dinv);
    scan_kernel<<<1, 256, 0, stream>>>(deg, offs);
    scatter_kernel<<<(N_EDGES + 255) / 256, 256, 0, stream>>>(rowp, colp, dinv, offs, cursor, csr);

    // weight + input splits
    convert_w<<<(N_LAYERS * NHID * NHID + NFEAT * NHID + 255) / 256, 256, 0, stream>>>(
        conv_w, wh, wl, lin0_w, w0h, w0l);
    convert_x<<<(N_NODES * NFEAT / 4 + 255) / 256, 256, 0, stream>>>(
        (const float4*)x, (ushort4*)xh, (ushort4*)xl);

    // lin0: x0 = relu(x @ W0 + b0)   [MFMA split-bf16 -> fp16]
    gemm_mfma<0><<<dim3(157, 2), 256, 0, stream>>>(
        xh, xl, w0h, w0l, lin0_b, x0, nullptr, N_NODES, NFEAT, 1.f, 0.f);

    u16* ph = xh;  // alias: x splits no longer needed
    u16* pl = xl;

    const __half* h_in = x0;
    for (int l = 0; l < N_LAYERS; ++l) {
        float beta = logf(0.5f / (float)(l + 1) + 1.0f);
        spmm_blend<<<2500, 256, 0, stream>>>(
            h_in, x0, offs, csr, dinv, (ushort4*)ph, (ushort4*)pl);
        gemm_mfma<1><<<dim3(157, 2), 256, 0, stream>>>(
            ph, pl, wh + (size_t)l * NHID * NHID, wl + (size_t)l * NHID * NHID,
            nullptr, outb, stats + l * 2 * NHID, N_NODES, NHID, beta, 1.f - beta);
        bn_final<<<1, 256, 0, stream>>>(stats + l * 2 * NHID, bn_g + l * NHID, bn_b + l * NHID, AB);
        bn_apply<<<2500, 256, 0, stream>>>(outb, AB, hbuf);
        h_in = hbuf;
    }

    // lin1: out = h @ W1 + b1
    gemm_lin1<<<dim3(157, 1), 256, 0, stream>>>(
        hbuf, lin1_w, lin1_b, outp, N_NODES, NCLASS, NHID);
}

// Round 7
// 654.864 us; speedup vs baseline: 1.7232x; 1.1141x over previous
//
#include <hip/hip_runtime.h>
#include <hip/hip_fp16.h>
#include <math.h>

#define N_NODES 10000
#define N_EDGES 320000
#define NFEAT 512
#define NHID 256
#define NCLASS 64
#define N_LAYERS 8
#define BN_EPS 1e-5f

typedef unsigned short u16;
typedef __attribute__((ext_vector_type(8))) short short8v;
typedef __attribute__((ext_vector_type(4))) float f32x4;

__device__ __forceinline__ u16 bf_hi_bits(float f) {
    unsigned u = __float_as_uint(f);
    unsigned r = (u + 0x7fffu + ((u >> 16) & 1u)) >> 16;
    return (u16)r;
}
__device__ __forceinline__ float bf_to_f(u16 h) {
    return __uint_as_float(((unsigned)h) << 16);
}
__device__ __forceinline__ float4 loadh4(const __half* p) {
    float2 raw = *(const float2*)p;
    __half2 h0 = *reinterpret_cast<const __half2*>(&raw.x);
    __half2 h1 = *reinterpret_cast<const __half2*>(&raw.y);
    float2 f0 = __half22float2(h0);
    float2 f1 = __half22float2(h1);
    return make_float4(f0.x, f0.y, f1.x, f1.y);
}

// ---------------- init: deg=1 (self loop), cursor=0, stats=0 ----------------
__global__ void init_kernel(int* __restrict__ deg, int* __restrict__ cursor,
                            float* __restrict__ stats) {
    int i = blockIdx.x * 256 + threadIdx.x;
    if (i < N_NODES) { deg[i] = 1; cursor[i] = 0; }
    if (i < N_LAYERS * 2 * NHID) stats[i] = 0.f;
}

__global__ void deg_count(const int* __restrict__ col, int* __restrict__ deg) {
    int e = blockIdx.x * 256 + threadIdx.x;
    if (e < N_EDGES) atomicAdd(&deg[col[e]], 1);
}

__global__ void dinv_kernel(const int* __restrict__ deg, float* __restrict__ dinv) {
    int i = blockIdx.x * 256 + threadIdx.x;
    if (i < N_NODES) dinv[i] = rsqrtf((float)deg[i]);
}

// ---------------- blocked single-kernel exclusive scan of (deg-1) -> offs[N+1] ----------------
// 256 threads x 40-element chunks: thread-local prefix (regs) + one block scan.
#define SCAN_CHUNK 40
__global__ void scan_kernel(const int* __restrict__ deg, int* __restrict__ offs) {
    __shared__ int tsum[256];
    int tid = threadIdx.x;
    int base = tid * SCAN_CHUNK;
    int local[SCAN_CHUNK];
    int s = 0;
    #pragma unroll
    for (int j = 0; j < SCAN_CHUNK; ++j) {
        int i = base + j;
        int v = (i < N_NODES) ? (deg[i] - 1) : 0;
        local[j] = s;
        s += v;
    }
    tsum[tid] = s;
    __syncthreads();
    #pragma unroll
    for (int off = 1; off < 256; off <<= 1) {
        int v = (tid >= off) ? tsum[tid - off] : 0;
        __syncthreads();
        tsum[tid] += v;
        __syncthreads();
    }
    int carry = (tid > 0) ? tsum[tid - 1] : 0;
    #pragma unroll
    for (int j = 0; j < SCAN_CHUNK; ++j) {
        int i = base + j;
        if (i < N_NODES) offs[i] = carry + local[j];
    }
    if (tid == 255) offs[N_NODES] = tsum[255];
}

__global__ void scatter_kernel(const int* __restrict__ row, const int* __restrict__ col,
                               const float* __restrict__ dinv, const int* __restrict__ offs,
                               int* __restrict__ cursor, int2* __restrict__ csr) {
    int e = blockIdx.x * 256 + threadIdx.x;
    if (e >= N_EDGES) return;
    int c = col[e], r = row[e];
    int pos = offs[c] + atomicAdd(&cursor[c], 1);
    float w = dinv[r] * dinv[c];
    csr[pos] = make_int2(r, __float_as_int(w));
}

// ---------------- split conversions ----------------
__global__ void convert_x(const float4* __restrict__ x4, ushort4* __restrict__ xh,
                          ushort4* __restrict__ xl) {
    int i = blockIdx.x * 256 + threadIdx.x;
    if (i >= N_NODES * NFEAT / 4) return;
    float4 v = x4[i];
    ushort4 h, l;
    h.x = bf_hi_bits(v.x); l.x = bf_hi_bits(v.x - bf_to_f(h.x));
    h.y = bf_hi_bits(v.y); l.y = bf_hi_bits(v.y - bf_to_f(h.y));
    h.z = bf_hi_bits(v.z); l.z = bf_hi_bits(v.z - bf_to_f(h.z));
    h.w = bf_hi_bits(v.w); l.w = bf_hi_bits(v.w - bf_to_f(h.w));
    xh[i] = h; xl[i] = l;
}

__global__ void convert_w(const float* __restrict__ cw, u16* __restrict__ wh, u16* __restrict__ wl,
                          const float* __restrict__ l0w, u16* __restrict__ w0h, u16* __restrict__ w0l) {
    int i = blockIdx.x * 256 + threadIdx.x;
    if (i < N_LAYERS * NHID * NHID) {
        int l = i >> 16, rem = i & 65535, n = rem & 255;   // k = rem >> 8
        float f = cw[i];
        u16 h = bf_hi_bits(f); u16 lo = bf_hi_bits(f - bf_to_f(h));
        int o = (l << 16) | (n << 8) | (rem >> 8);
        wh[o] = h; wl[o] = lo;
    } else {
        int j = i - N_LAYERS * NHID * NHID;
        if (j < NFEAT * NHID) {
            int k = j >> 8, n = j & 255;
            float f = l0w[j];
            u16 h = bf_hi_bits(f); u16 lo = bf_hi_bits(f - bf_to_f(h));
            int o = n * NFEAT + k;
            w0h[o] = h; w0l[o] = lo;
        }
    }
}

// ---------------- fused SpMM: gather src, apply BN(+relu) on the fly, blend, emit split-bf16 ----------------
// BN=0: src rows used as-is through relu (layer 0, src=x0 which is already relu'd -> identity).
// BN=1: row value = relu(A*v + B) with A,B recomputed per-lane from stats/gamma/beta (prev layer).
template<int BN>
__global__ __launch_bounds__(256)
void spmm_blend(const __half* __restrict__ src, const __half* __restrict__ x0b,
                const int* __restrict__ offs, const int2* __restrict__ csr,
                const float* __restrict__ dinv,
                const float* __restrict__ stats, const float* __restrict__ g,
                const float* __restrict__ b,
                ushort4* __restrict__ ph, ushort4* __restrict__ pl) {
    int wid = threadIdx.x >> 6;
    int lane = threadIdx.x & 63;
    int v = blockIdx.x * 4 + wid;
    if (v >= N_NODES) return;
    int f0 = lane * 4;

    float4 A4 = make_float4(1.f, 1.f, 1.f, 1.f);
    float4 B4 = make_float4(0.f, 0.f, 0.f, 0.f);
    if (BN) {
        float4 sv = *(const float4*)&stats[f0];
        float4 qv = *(const float4*)&stats[NHID + f0];
        float4 gv = *(const float4*)&g[f0];
        float4 bv = *(const float4*)&b[f0];
        const float inv = 1.f / N_NODES;
        float mu, var, rs;
        mu = sv.x * inv; var = qv.x * inv - mu * mu; rs = rsqrtf(var + BN_EPS);
        A4.x = gv.x * rs; B4.x = bv.x - mu * A4.x;
        mu = sv.y * inv; var = qv.y * inv - mu * mu; rs = rsqrtf(var + BN_EPS);
        A4.y = gv.y * rs; B4.y = bv.y - mu * A4.y;
        mu = sv.z * inv; var = qv.z * inv - mu * mu; rs = rsqrtf(var + BN_EPS);
        A4.z = gv.z * rs; B4.z = bv.z - mu * A4.z;
        mu = sv.w * inv; var = qv.w * inv - mu * mu; rs = rsqrtf(var + BN_EPS);
        A4.w = gv.w * rs; B4.w = bv.w - mu * A4.w;
    }
    auto tf = [&](float4 r) {
        float4 o;
        if (BN) {
            o.x = fmaxf(fmaf(r.x, A4.x, B4.x), 0.f);
            o.y = fmaxf(fmaf(r.y, A4.y, B4.y), 0.f);
            o.z = fmaxf(fmaf(r.z, A4.z, B4.z), 0.f);
            o.w = fmaxf(fmaf(r.w, A4.w, B4.w), 0.f);
        } else {
            o.x = fmaxf(r.x, 0.f); o.y = fmaxf(r.y, 0.f);
            o.z = fmaxf(r.z, 0.f); o.w = fmaxf(r.w, 0.f);
        }
        return o;
    };

    size_t base = (size_t)v * NHID + f0;
    float dv = dinv[v];
    float sw = dv * dv;
    float4 a0 = tf(loadh4(src + base));    // self loop
    a0.x *= sw; a0.y *= sw; a0.z *= sw; a0.w *= sw;
    float4 a1 = make_float4(0.f, 0.f, 0.f, 0.f);
    int beg = offs[v], end = offs[v + 1];
    int e = beg;
    for (; e + 1 < end; e += 2) {
        int2 s0 = csr[e];
        int2 s1 = csr[e + 1];
        float w0 = __int_as_float(s0.y);
        float w1 = __int_as_float(s1.y);
        float4 h0 = tf(loadh4(src + (size_t)s0.x * NHID + f0));
        float4 h1 = tf(loadh4(src + (size_t)s1.x * NHID + f0));
        a0.x = fmaf(w0, h0.x, a0.x); a1.x = fmaf(w1, h1.x, a1.x);
        a0.y = fmaf(w0, h0.y, a0.y); a1.y = fmaf(w1, h1.y, a1.y);
        a0.z = fmaf(w0, h0.z, a0.z); a1.z = fmaf(w1, h1.z, a1.z);
        a0.w = fmaf(w0, h0.w, a0.w); a1.w = fmaf(w1, h1.w, a1.w);
    }
    if (e < end) {
        int2 s0 = csr[e];
        float w0 = __int_as_float(s0.y);
        float4 h0 = tf(loadh4(src + (size_t)s0.x * NHID + f0));
        a0.x = fmaf(w0, h0.x, a0.x);
        a0.y = fmaf(w0, h0.y, a0.y);
        a0.z = fmaf(w0, h0.z, a0.z);
        a0.w = fmaf(w0, h0.w, a0.w);
    }
    float4 xv = loadh4(x0b + base);
    float4 r;
    r.x = 0.9f * (a0.x + a1.x) + 0.1f * xv.x;
    r.y = 0.9f * (a0.y + a1.y) + 0.1f * xv.y;
    r.z = 0.9f * (a0.z + a1.z) + 0.1f * xv.z;
    r.w = 0.9f * (a0.w + a1.w) + 0.1f * xv.w;
    ushort4 hh, ll;
    hh.x = bf_hi_bits(r.x); ll.x = bf_hi_bits(r.x - bf_to_f(hh.x));
    hh.y = bf_hi_bits(r.y); ll.y = bf_hi_bits(r.y - bf_to_f(hh.y));
    hh.z = bf_hi_bits(r.z); ll.z = bf_hi_bits(r.z - bf_to_f(hh.z));
    hh.w = bf_hi_bits(r.w); ll.w = bf_hi_bits(r.w - bf_to_f(hh.w));
    ph[(size_t)v * 64 + lane] = hh;
    pl[(size_t)v * 64 + lane] = ll;
}

// ---------------- split-bf16 MFMA GEMM ----------------
// MODE 0: out = relu(acc + bias)       (lin0 -> x0 fp16)
// MODE 1: out = alpha*acc + rcoef*(Ah+Al); fused BN column sums (fp32, pre-rounding)
template<int MODE>
__global__ __launch_bounds__(256)
void gemm_mfma(const u16* __restrict__ Ah, const u16* __restrict__ Al,
               const u16* __restrict__ BTh, const u16* __restrict__ BTl,
               const float* __restrict__ bias, __half* __restrict__ C,
               float* __restrict__ stats, int M, int K,
               float alpha, float rcoef) {
    __shared__ u16 As_h[64][40], As_l[64][40];
    __shared__ u16 Bs_h[128][40], Bs_l[128][40];
    int tid = threadIdx.x;
    int lane = tid & 63, wid = tid >> 6;
    int wr = wid >> 1, wc = wid & 1;
    int brow = blockIdx.x * 64;
    int bcol = blockIdx.y * 128;

    f32x4 acc[2][4];
    #pragma unroll
    for (int i = 0; i < 2; ++i)
        #pragma unroll
        for (int j = 0; j < 4; ++j) { acc[i][j].x = 0.f; acc[i][j].y = 0.f; acc[i][j].z = 0.f; acc[i][j].w = 0.f; }

    int am = tid >> 2, akc = (tid & 3) * 8;
    int bn = tid >> 1, bkc = (tid & 1) * 16;
    bool aval = (brow + am) < M;
    size_t arow_off = (size_t)(brow + am) * K + akc;
    size_t brow_off = (size_t)(bcol + bn) * K + bkc;
    int rlo = lane & 15, kg = (lane >> 4) * 8;

    for (int k0 = 0; k0 < K; k0 += 32) {
        uint4 z4 = make_uint4(0, 0, 0, 0);
        uint4 a_h = aval ? *(const uint4*)(Ah + arow_off + k0) : z4;
        uint4 a_l = aval ? *(const uint4*)(Al + arow_off + k0) : z4;
        uint4 b_h0 = *(const uint4*)(BTh + brow_off + k0);
        uint4 b_h1 = *(const uint4*)(BTh + brow_off + k0 + 8);
        uint4 b_l0 = *(const uint4*)(BTl + brow_off + k0);
        uint4 b_l1 = *(const uint4*)(BTl + brow_off + k0 + 8);
        __syncthreads();
        *(uint4*)&As_h[am][akc] = a_h;
        *(uint4*)&As_l[am][akc] = a_l;
        *(uint4*)&Bs_h[bn][bkc] = b_h0;
        *(uint4*)&Bs_h[bn][bkc + 8] = b_h1;
        *(uint4*)&Bs_l[bn][bkc] = b_l0;
        *(uint4*)&Bs_l[bn][bkc + 8] = b_l1;
        __syncthreads();

        short8v afh[2], afl[2], bfh[4], bfl[4];
        #pragma unroll
        for (int mf = 0; mf < 2; ++mf) {
            afh[mf] = *(const short8v*)&As_h[wr * 32 + mf * 16 + rlo][kg];
            afl[mf] = *(const short8v*)&As_l[wr * 32 + mf * 16 + rlo][kg];
        }
        #pragma unroll
        for (int nf = 0; nf < 4; ++nf) {
            bfh[nf] = *(const short8v*)&Bs_h[wc * 64 + nf * 16 + rlo][kg];
            bfl[nf] = *(const short8v*)&Bs_l[wc * 64 + nf * 16 + rlo][kg];
        }
        #pragma unroll
        for (int mf = 0; mf < 2; ++mf)
            #pragma unroll
            for (int nf = 0; nf < 4; ++nf) {
                acc[mf][nf] = __builtin_amdgcn_mfma_f32_16x16x32_bf16(afl[mf], bfh[nf], acc[mf][nf], 0, 0, 0);
                acc[mf][nf] = __builtin_amdgcn_mfma_f32_16x16x32_bf16(afh[mf], bfl[nf], acc[mf][nf], 0, 0, 0);
                acc[mf][nf] = __builtin_amdgcn_mfma_f32_16x16x32_bf16(afh[mf], bfh[nf], acc[mf][nf], 0, 0, 0);
            }
    }

    // epilogue: D layout col=lane&15, row=(lane>>4)*4+reg  [m89-verified]
    int r0 = brow + wr * 32 + (lane >> 4) * 4;
    #pragma unroll
    for (int nf = 0; nf < 4; ++nf) {
        int c = bcol + wc * 64 + nf * 16 + rlo;
        float s = 0.f, s2 = 0.f;
        float bv = (MODE == 0) ? bias[c] : 0.f;
        #pragma unroll
        for (int mf = 0; mf < 2; ++mf) {
            #pragma unroll
            for (int reg = 0; reg < 4; ++reg) {
                int rr = r0 + mf * 16 + reg;
                if (rr < M) {
                    float o;
                    if (MODE == 0) {
                        o = fmaxf(acc[mf][nf][reg] + bv, 0.f);
                    } else {
                        size_t pi = (size_t)rr * K + c;   // K == NHID in conv mode
                        float p = bf_to_f(Ah[pi]) + bf_to_f(Al[pi]);
                        o = alpha * acc[mf][nf][reg] + rcoef * p;
                        s += o; s2 = fmaf(o, o, s2);
                    }
                    C[(size_t)rr * NHID + c] = __float2half(o);
                }
            }
        }
        if (MODE == 1) {
            s  += __shfl_xor(s, 16);  s  += __shfl_xor(s, 32);
            s2 += __shfl_xor(s2, 16); s2 += __shfl_xor(s2, 32);
            if (lane < 16) {
                atomicAdd(&stats[c], s);
                atomicAdd(&stats[NHID + c], s2);
            }
        }
    }
}

// ---------------- lin1 GEMM with fused BN+relu on A (A = raw conv output fp16) ----------------
__global__ __launch_bounds__(256)
void gemm_lin1(const __half* __restrict__ A, const float* __restrict__ B,
               const float* __restrict__ bias, float* __restrict__ C,
               const float* __restrict__ stats, const float* __restrict__ g,
               const float* __restrict__ b,
               int M, int Nc, int K) {
    __shared__ float As[16][68];
    __shared__ float Bs[16][68];
    __shared__ float ABs[2][NHID];
    int tid = threadIdx.x;
    {   // build BN affine table once (features = K = 256)
        float mu = stats[tid] * (1.f / N_NODES);
        float var = stats[NHID + tid] * (1.f / N_NODES) - mu * mu;
        float rs = rsqrtf(var + BN_EPS);
        float a = g[tid] * rs;
        ABs[0][tid] = a;
        ABs[1][tid] = b[tid] - mu * a;
    }
    __syncthreads();
    int tc = tid & 15, tr = tid >> 4;
    int brow = blockIdx.x * 64, bcol = blockIdx.y * 64;
    float acc[4][4] = {};
    int arow = tid >> 2;
    int ak = (tid & 3) * 4;
    int bkrow = tid >> 4;
    int bcol4 = (tid & 15) * 4;

    for (int k0 = 0; k0 < K; k0 += 16) {
        int gr = brow + arow;
        float4 av = (gr < M) ? loadh4(A + (size_t)gr * K + k0 + ak)
                             : make_float4(0.f, 0.f, 0.f, 0.f);
        av.x = fmaxf(fmaf(av.x, ABs[0][k0 + ak + 0], ABs[1][k0 + ak + 0]), 0.f);
        av.y = fmaxf(fmaf(av.y, ABs[0][k0 + ak + 1], ABs[1][k0 + ak + 1]), 0.f);
        av.z = fmaxf(fmaf(av.z, ABs[0][k0 + ak + 2], ABs[1][k0 + ak + 2]), 0.f);
        av.w = fmaxf(fmaf(av.w, ABs[0][k0 + ak + 3], ABs[1][k0 + ak + 3]), 0.f);
        As[ak + 0][arow] = av.x;
        As[ak + 1][arow] = av.y;
        As[ak + 2][arow] = av.z;
        As[ak + 3][arow] = av.w;
        float4 bv = *(const float4*)&B[(size_t)(k0 + bkrow) * Nc + bcol + bcol4];
        *(float4*)&Bs[bkrow][bcol4] = bv;
        __syncthreads();
        #pragma unroll
        for (int kk = 0; kk < 16; ++kk) {
            float4 a = *(const float4*)&As[kk][tr * 4];
            float4 b2 = *(const float4*)&Bs[kk][tc * 4];
            acc[0][0] = fmaf(a.x, b2.x, acc[0][0]);
            acc[0][1] = fmaf(a.x, b2.y, acc[0][1]);
            acc[0][2] = fmaf(a.x, b2.z, acc[0][2]);
            acc[0][3] = fmaf(a.x, b2.w, acc[0][3]);
            acc[1][0] = fmaf(a.y, b2.x, acc[1][0]);
            acc[1][1] = fmaf(a.y, b2.y, acc[1][1]);
            acc[1][2] = fmaf(a.y, b2.z, acc[1][2]);
            acc[1][3] = fmaf(a.y, b2.w, acc[1][3]);
            acc[2][0] = fmaf(a.z, b2.x, acc[2][0]);
            acc[2][1] = fmaf(a.z, b2.y, acc[2][1]);
            acc[2][2] = fmaf(a.z, b2.z, acc[2][2]);
            acc[2][3] = fmaf(a.z, b2.w, acc[2][3]);
            acc[3][0] = fmaf(a.w, b2.x, acc[3][0]);
            acc[3][1] = fmaf(a.w, b2.y, acc[3][1]);
            acc[3][2] = fmaf(a.w, b2.z, acc[3][2]);
            acc[3][3] = fmaf(a.w, b2.w, acc[3][3]);
        }
        __syncthreads();
    }

    int r0 = brow + tr * 4, c0 = bcol + tc * 4;
    float4 b4 = *(const float4*)&bias[c0];
    #pragma unroll
    for (int i = 0; i < 4; ++i) {
        int r = r0 + i;
        if (r >= M) continue;
        float4 o;
        o.x = acc[i][0] + b4.x;
        o.y = acc[i][1] + b4.y;
        o.z = acc[i][2] + b4.z;
        o.w = acc[i][3] + b4.w;
        *(float4*)&C[(size_t)r * Nc + c0] = o;
    }
}

// ---------------- host ----------------
static inline size_t align_up(size_t x, size_t a) { return (x + a - 1) & ~(a - 1); }

extern "C" void kernel_launch(void* const* d_in, const int* in_sizes, int n_in,
                              void* d_out, int out_size, void* d_ws, size_t ws_size,
                              hipStream_t stream) {
    const float* x       = (const float*)d_in[0];
    const int*   ei      = (const int*)d_in[1];
    const float* lin0_w  = (const float*)d_in[2];
    const float* lin0_b  = (const float*)d_in[3];
    const float* lin1_w  = (const float*)d_in[4];
    const float* lin1_b  = (const float*)d_in[5];
    const float* conv_w  = (const float*)d_in[6];
    const float* bn_g    = (const float*)d_in[7];
    const float* bn_b    = (const float*)d_in[8];
    const int* rowp = ei;
    const int* colp = ei + N_EDGES;
    float* outp = (float*)d_out;

    char* ws = (char*)d_ws;
    size_t off = 0;
    auto alloc = [&](size_t bytes) { size_t o = off; off = align_up(off + bytes, 256); return ws + o; };
    int*    deg    = (int*)alloc(N_NODES * 4);
    int*    cursor = (int*)alloc(N_NODES * 4);
    int*    offs   = (int*)alloc((N_NODES + 1) * 4);
    float*  dinv   = (float*)alloc(N_NODES * 4);
    int2*   csr    = (int2*)alloc((size_t)N_EDGES * 8);
    __half* x0     = (__half*)alloc((size_t)N_NODES * NHID * 2);
    __half* outb   = (__half*)alloc((size_t)N_NODES * NHID * 2);
    float*  stats  = (float*)alloc(N_LAYERS * 2 * NHID * 4);
    u16*    xh     = (u16*)alloc((size_t)N_NODES * NFEAT * 2);  // reused as p_hi after lin0
    u16*    xl     = (u16*)alloc((size_t)N_NODES * NFEAT * 2);  // reused as p_lo after lin0
    u16*    wh     = (u16*)alloc((size_t)N_LAYERS * NHID * NHID * 2);
    u16*    wl     = (u16*)alloc((size_t)N_LAYERS * NHID * NHID * 2);
    u16*    w0h    = (u16*)alloc((size_t)NFEAT * NHID * 2);
    u16*    w0l    = (u16*)alloc((size_t)NFEAT * NHID * 2);
    (void)ws_size; (void)n_in; (void)in_sizes; (void)out_size;

    // graph preprocessing
    init_kernel<<<40, 256, 0, stream>>>(deg, cursor, stats);
    deg_count<<<(N_EDGES + 255) / 256, 256, 0, stream>>>(colp, deg);
    dinv_kernel<<<(N_NODES + 255) / 256, 256, 0, stream>>>(deg, dinv);
    scan_kernel<<<1, 256, 0, stream>>>(deg, offs);
    scatter_kernel<<<(N_EDGES + 255) / 256, 256, 0, stream>>>(rowp, colp, dinv, offs, cursor, csr);

    // weight + input splits
    convert_w<<<(N_LAYERS * NHID * NHID + NFEAT * NHID + 255) / 256, 256, 0, stream>>>(
        conv_w, wh, wl, lin0_w, w0h, w0l);
    convert_x<<<(N_NODES * NFEAT / 4 + 255) / 256, 256, 0, stream>>>(
        (const float4*)x, (ushort4*)xh, (ushort4*)xl);

    // lin0: x0 = relu(x @ W0 + b0)   [MFMA split-bf16 -> fp16]
    gemm_mfma<0><<<dim3(157, 2), 256, 0, stream>>>(
        xh, xl, w0h, w0l, lin0_b, x0, nullptr, N_NODES, NFEAT, 1.f, 0.f);

    u16* ph = xh;  // alias: x splits no longer needed
    u16* pl = xl;

    for (int l = 0; l < N_LAYERS; ++l) {
        float beta = logf(0.5f / (float)(l + 1) + 1.0f);
        if (l == 0) {
            spmm_blend<0><<<2500, 256, 0, stream>>>(
                x0, x0, offs, csr, dinv, nullptr, nullptr, nullptr,
                (ushort4*)ph, (ushort4*)pl);
        } else {
            spmm_blend<1><<<2500, 256, 0, stream>>>(
                outb, x0, offs, csr, dinv,
                stats + (l - 1) * 2 * NHID, bn_g + (l - 1) * NHID, bn_b + (l - 1) * NHID,
                (ushort4*)ph, (ushort4*)pl);
        }
        gemm_mfma<1><<<dim3(157, 2), 256, 0, stream>>>(
            ph, pl, wh + (size_t)l * NHID * NHID, wl + (size_t)l * NHID * NHID,
            nullptr, outb, stats + l * 2 * NHID, N_NODES, NHID, beta, 1.f - beta);
    }

    // lin1: out = relu_bn(outb_l7) @ W1 + b1  [BN folded into A-load]
    gemm_lin1<<<dim3(157, 1), 256, 0, stream>>>(
        outb, lin1_w, lin1_b, outp,
        stats + 7 * 2 * NHID, bn_g + 7 * NHID, bn_b + 7 * NHID,
        N_NODES, NCLASS, NHID);
}

// Round 11
// 601.234 us; speedup vs baseline: 1.8769x; 1.0892x over previous
//
#include <hip/hip_runtime.h>
#include <hip/hip_fp16.h>
#include <math.h>

#define N_NODES 10000
#define N_EDGES 320000
#define NFEAT 512
#define NHID 256
#define NCLASS 64
#define N_LAYERS 8
#define BN_EPS 1e-5f

typedef unsigned short u16;
typedef __attribute__((ext_vector_type(8))) short short8v;
typedef __attribute__((ext_vector_type(4))) float f32x4;

__device__ __forceinline__ u16 bf_hi_bits(float f) {
    unsigned u = __float_as_uint(f);
    unsigned r = (u + 0x7fffu + ((u >> 16) & 1u)) >> 16;
    return (u16)r;
}
__device__ __forceinline__ float bf_to_f(u16 h) {
    return __uint_as_float(((unsigned)h) << 16);
}
__device__ __forceinline__ float4 loadh4(const __half* p) {
    float2 raw = *(const float2*)p;
    __half2 h0 = *reinterpret_cast<const __half2*>(&raw.x);
    __half2 h1 = *reinterpret_cast<const __half2*>(&raw.y);
    float2 f0 = __half22float2(h0);
    float2 f1 = __half22float2(h1);
    return make_float4(f0.x, f0.y, f1.x, f1.y);
}

// ---------------- init: deg=1 (self loop), cursor=0, stats=0 ----------------
__global__ void init_kernel(int* __restrict__ deg, int* __restrict__ cursor,
                            float* __restrict__ stats) {
    int i = blockIdx.x * 256 + threadIdx.x;
    if (i < N_NODES) { deg[i] = 1; cursor[i] = 0; }
    if (i < N_LAYERS * 2 * NHID) stats[i] = 0.f;
}

__global__ void deg_count(const int* __restrict__ col, int* __restrict__ deg) {
    int e = blockIdx.x * 256 + threadIdx.x;
    if (e < N_EDGES) atomicAdd(&deg[col[e]], 1);
}

__global__ void dinv_kernel(const int* __restrict__ deg, float* __restrict__ dinv) {
    int i = blockIdx.x * 256 + threadIdx.x;
    if (i < N_NODES) dinv[i] = rsqrtf((float)deg[i]);
}

// ---------------- blocked single-kernel exclusive scan of (deg-1) -> offs[N+1] ----------------
#define SCAN_CHUNK 40
__global__ void scan_kernel(const int* __restrict__ deg, int* __restrict__ offs) {
    __shared__ int tsum[256];
    int tid = threadIdx.x;
    int base = tid * SCAN_CHUNK;
    int local[SCAN_CHUNK];
    int s = 0;
    #pragma unroll
    for (int j = 0; j < SCAN_CHUNK; ++j) {
        int i = base + j;
        int v = (i < N_NODES) ? (deg[i] - 1) : 0;
        local[j] = s;
        s += v;
    }
    tsum[tid] = s;
    __syncthreads();
    #pragma unroll
    for (int off = 1; off < 256; off <<= 1) {
        int v = (tid >= off) ? tsum[tid - off] : 0;
        __syncthreads();
        tsum[tid] += v;
        __syncthreads();
    }
    int carry = (tid > 0) ? tsum[tid - 1] : 0;
    #pragma unroll
    for (int j = 0; j < SCAN_CHUNK; ++j) {
        int i = base + j;
        if (i < N_NODES) offs[i] = carry + local[j];
    }
    if (tid == 255) offs[N_NODES] = tsum[255];
}

__global__ void scatter_kernel(const int* __restrict__ row, const int* __restrict__ col,
                               const float* __restrict__ dinv, const int* __restrict__ offs,
                               int* __restrict__ cursor, int2* __restrict__ csr) {
    int e = blockIdx.x * 256 + threadIdx.x;
    if (e >= N_EDGES) return;
    int c = col[e], r = row[e];
    int pos = offs[c] + atomicAdd(&cursor[c], 1);
    float w = dinv[r] * dinv[c];
    csr[pos] = make_int2(r, __float_as_int(w));
}

// ---------------- split conversions ----------------
__global__ void convert_x(const float4* __restrict__ x4, ushort4* __restrict__ xh,
                          ushort4* __restrict__ xl) {
    int i = blockIdx.x * 256 + threadIdx.x;
    if (i >= N_NODES * NFEAT / 4) return;
    float4 v = x4[i];
    ushort4 h, l;
    h.x = bf_hi_bits(v.x); l.x = bf_hi_bits(v.x - bf_to_f(h.x));
    h.y = bf_hi_bits(v.y); l.y = bf_hi_bits(v.y - bf_to_f(h.y));
    h.z = bf_hi_bits(v.z); l.z = bf_hi_bits(v.z - bf_to_f(h.z));
    h.w = bf_hi_bits(v.w); l.w = bf_hi_bits(v.w - bf_to_f(h.w));
    xh[i] = h; xl[i] = l;
}

__global__ void convert_w(const float* __restrict__ cw, u16* __restrict__ wh, u16* __restrict__ wl,
                          const float* __restrict__ l0w, u16* __restrict__ w0h, u16* __restrict__ w0l) {
    int i = blockIdx.x * 256 + threadIdx.x;
    if (i < N_LAYERS * NHID * NHID) {
        int l = i >> 16, rem = i & 65535, n = rem & 255;   // k = rem >> 8
        float f = cw[i];
        u16 h = bf_hi_bits(f); u16 lo = bf_hi_bits(f - bf_to_f(h));
        int o = (l << 16) | (n << 8) | (rem >> 8);
        wh[o] = h; wl[o] = lo;
    } else {
        int j = i - N_LAYERS * NHID * NHID;
        if (j < NFEAT * NHID) {
            int k = j >> 8, n = j & 255;
            float f = l0w[j];
            u16 h = bf_hi_bits(f); u16 lo = bf_hi_bits(f - bf_to_f(h));
            int o = n * NFEAT + k;
            w0h[o] = h; w0l[o] = lo;
        }
    }
}

// ---------------- fused SpMM: gather src, BN(+relu) on the fly, blend, emit split-bf16 ----------------
// 4-edge unroll, 4 independent accumulators => 4 gather loads in flight per wave.
template<int BN>
__global__ __launch_bounds__(256)
void spmm_blend(const __half* __restrict__ src, const __half* __restrict__ x0b,
                const int* __restrict__ offs, const int2* __restrict__ csr,
                const float* __restrict__ dinv,
                const float* __restrict__ stats, const float* __restrict__ g,
                const float* __restrict__ b,
                ushort4* __restrict__ ph, ushort4* __restrict__ pl) {
    int wid = threadIdx.x >> 6;
    int lane = threadIdx.x & 63;
    int v = blockIdx.x * 4 + wid;
    if (v >= N_NODES) return;
    int f0 = lane * 4;

    float4 A4 = make_float4(1.f, 1.f, 1.f, 1.f);
    float4 B4 = make_float4(0.f, 0.f, 0.f, 0.f);
    if (BN) {
        float4 sv = *(const float4*)&stats[f0];
        float4 qv = *(const float4*)&stats[NHID + f0];
        float4 gv = *(const float4*)&g[f0];
        float4 bv = *(const float4*)&b[f0];
        const float inv = 1.f / N_NODES;
        float mu, var, rs;
        mu = sv.x * inv; var = qv.x * inv - mu * mu; rs = rsqrtf(var + BN_EPS);
        A4.x = gv.x * rs; B4.x = bv.x - mu * A4.x;
        mu = sv.y * inv; var = qv.y * inv - mu * mu; rs = rsqrtf(var + BN_EPS);
        A4.y = gv.y * rs; B4.y = bv.y - mu * A4.y;
        mu = sv.z * inv; var = qv.z * inv - mu * mu; rs = rsqrtf(var + BN_EPS);
        A4.z = gv.z * rs; B4.z = bv.z - mu * A4.z;
        mu = sv.w * inv; var = qv.w * inv - mu * mu; rs = rsqrtf(var + BN_EPS);
        A4.w = gv.w * rs; B4.w = bv.w - mu * A4.w;
    }
    auto tf = [&](float4 r) {
        float4 o;
        if (BN) {
            o.x = fmaxf(fmaf(r.x, A4.x, B4.x), 0.f);
            o.y = fmaxf(fmaf(r.y, A4.y, B4.y), 0.f);
            o.z = fmaxf(fmaf(r.z, A4.z, B4.z), 0.f);
            o.w = fmaxf(fmaf(r.w, A4.w, B4.w), 0.f);
        } else {
            o.x = fmaxf(r.x, 0.f); o.y = fmaxf(r.y, 0.f);
            o.z = fmaxf(r.z, 0.f); o.w = fmaxf(r.w, 0.f);
        }
        return o;
    };

    size_t base = (size_t)v * NHID + f0;
    float dv = dinv[v];
    float sw = dv * dv;
    float4 a0 = tf(loadh4(src + base));    // self loop
    a0.x *= sw; a0.y *= sw; a0.z *= sw; a0.w *= sw;
    float4 a1 = make_float4(0.f, 0.f, 0.f, 0.f);
    float4 a2 = make_float4(0.f, 0.f, 0.f, 0.f);
    float4 a3 = make_float4(0.f, 0.f, 0.f, 0.f);
    int beg = offs[v], end = offs[v + 1];
    int e = beg;
    for (; e + 3 < end; e += 4) {
        int2 s0 = csr[e];
        int2 s1 = csr[e + 1];
        int2 s2 = csr[e + 2];
        int2 s3 = csr[e + 3];
        float w0 = __int_as_float(s0.y);
        float w1 = __int_as_float(s1.y);
        float w2 = __int_as_float(s2.y);
        float w3 = __int_as_float(s3.y);
        float4 h0 = tf(loadh4(src + (size_t)s0.x * NHID + f0));
        float4 h1 = tf(loadh4(src + (size_t)s1.x * NHID + f0));
        float4 h2 = tf(loadh4(src + (size_t)s2.x * NHID + f0));
        float4 h3 = tf(loadh4(src + (size_t)s3.x * NHID + f0));
        a0.x = fmaf(w0, h0.x, a0.x); a1.x = fmaf(w1, h1.x, a1.x);
        a2.x = fmaf(w2, h2.x, a2.x); a3.x = fmaf(w3, h3.x, a3.x);
        a0.y = fmaf(w0, h0.y, a0.y); a1.y = fmaf(w1, h1.y, a1.y);
        a2.y = fmaf(w2, h2.y, a2.y); a3.y = fmaf(w3, h3.y, a3.y);
        a0.z = fmaf(w0, h0.z, a0.z); a1.z = fmaf(w1, h1.z, a1.z);
        a2.z = fmaf(w2, h2.z, a2.z); a3.z = fmaf(w3, h3.z, a3.z);
        a0.w = fmaf(w0, h0.w, a0.w); a1.w = fmaf(w1, h1.w, a1.w);
        a2.w = fmaf(w2, h2.w, a2.w); a3.w = fmaf(w3, h3.w, a3.w);
    }
    for (; e < end; ++e) {
        int2 s0 = csr[e];
        float w0 = __int_as_float(s0.y);
        float4 h0 = tf(loadh4(src + (size_t)s0.x * NHID + f0));
        a0.x = fmaf(w0, h0.x, a0.x);
        a0.y = fmaf(w0, h0.y, a0.y);
        a0.z = fmaf(w0, h0.z, a0.z);
        a0.w = fmaf(w0, h0.w, a0.w);
    }
    float4 xv = loadh4(x0b + base);
    float4 r;
    r.x = 0.9f * ((a0.x + a1.x) + (a2.x + a3.x)) + 0.1f * xv.x;
    r.y = 0.9f * ((a0.y + a1.y) + (a2.y + a3.y)) + 0.1f * xv.y;
    r.z = 0.9f * ((a0.z + a1.z) + (a2.z + a3.z)) + 0.1f * xv.z;
    r.w = 0.9f * ((a0.w + a1.w) + (a2.w + a3.w)) + 0.1f * xv.w;
    ushort4 hh, ll;
    hh.x = bf_hi_bits(r.x); ll.x = bf_hi_bits(r.x - bf_to_f(hh.x));
    hh.y = bf_hi_bits(r.y); ll.y = bf_hi_bits(r.y - bf_to_f(hh.y));
    hh.z = bf_hi_bits(r.z); ll.z = bf_hi_bits(r.z - bf_to_f(hh.z));
    hh.w = bf_hi_bits(r.w); ll.w = bf_hi_bits(r.w - bf_to_f(hh.w));
    ph[(size_t)v * 64 + lane] = hh;
    pl[(size_t)v * 64 + lane] = ll;
}

// ---------------- split-bf16 MFMA GEMM ----------------
// MODE 0: out = relu(acc + bias)       (lin0 -> x0 fp16)
// MODE 1: out = alpha*acc + rcoef*(Ah+Al); fused BN column sums (fp32, pre-rounding)
template<int MODE>
__global__ __launch_bounds__(256)
void gemm_mfma(const u16* __restrict__ Ah, const u16* __restrict__ Al,
               const u16* __restrict__ BTh, const u16* __restrict__ BTl,
               const float* __restrict__ bias, __half* __restrict__ C,
               float* __restrict__ stats, int M, int K,
               float alpha, float rcoef) {
    __shared__ u16 As_h[64][40], As_l[64][40];
    __shared__ u16 Bs_h[128][40], Bs_l[128][40];
    int tid = threadIdx.x;
    int lane = tid & 63, wid = tid >> 6;
    int wr = wid >> 1, wc = wid & 1;
    int brow = blockIdx.x * 64;
    int bcol = blockIdx.y * 128;

    f32x4 acc[2][4];
    #pragma unroll
    for (int i = 0; i < 2; ++i)
        #pragma unroll
        for (int j = 0; j < 4; ++j) { acc[i][j].x = 0.f; acc[i][j].y = 0.f; acc[i][j].z = 0.f; acc[i][j].w = 0.f; }

    int am = tid >> 2, akc = (tid & 3) * 8;
    int bn = tid >> 1, bkc = (tid & 1) * 16;
    bool aval = (brow + am) < M;
    size_t arow_off = (size_t)(brow + am) * K + akc;
    size_t brow_off = (size_t)(bcol + bn) * K + bkc;
    int rlo = lane & 15, kg = (lane >> 4) * 8;

    for (int k0 = 0; k0 < K; k0 += 32) {
        uint4 z4 = make_uint4(0, 0, 0, 0);
        uint4 a_h = aval ? *(const uint4*)(Ah + arow_off + k0) : z4;
        uint4 a_l = aval ? *(const uint4*)(Al + arow_off + k0) : z4;
        uint4 b_h0 = *(const uint4*)(BTh + brow_off + k0);
        uint4 b_h1 = *(const uint4*)(BTh + brow_off + k0 + 8);
        uint4 b_l0 = *(const uint4*)(BTl + brow_off + k0);
        uint4 b_l1 = *(const uint4*)(BTl + brow_off + k0 + 8);
        __syncthreads();
        *(uint4*)&As_h[am][akc] = a_h;
        *(uint4*)&As_l[am][akc] = a_l;
        *(uint4*)&Bs_h[bn][bkc] = b_h0;
        *(uint4*)&Bs_h[bn][bkc + 8] = b_h1;
        *(uint4*)&Bs_l[bn][bkc] = b_l0;
        *(uint4*)&Bs_l[bn][bkc + 8] = b_l1;
        __syncthreads();

        short8v afh[2], afl[2], bfh[4], bfl[4];
        #pragma unroll
        for (int mf = 0; mf < 2; ++mf) {
            afh[mf] = *(const short8v*)&As_h[wr * 32 + mf * 16 + rlo][kg];
            afl[mf] = *(const short8v*)&As_l[wr * 32 + mf * 16 + rlo][kg];
        }
        #pragma unroll
        for (int nf = 0; nf < 4; ++nf) {
            bfh[nf] = *(const short8v*)&Bs_h[wc * 64 + nf * 16 + rlo][kg];
            bfl[nf] = *(const short8v*)&Bs_l[wc * 64 + nf * 16 + rlo][kg];
        }
        #pragma unroll
        for (int mf = 0; mf < 2; ++mf)
            #pragma unroll
            for (int nf = 0; nf < 4; ++nf) {
                acc[mf][nf] = __builtin_amdgcn_mfma_f32_16x16x32_bf16(afl[mf], bfh[nf], acc[mf][nf], 0, 0, 0);
                acc[mf][nf] = __builtin_amdgcn_mfma_f32_16x16x32_bf16(afh[mf], bfl[nf], acc[mf][nf], 0, 0, 0);
                acc[mf][nf] = __builtin_amdgcn_mfma_f32_16x16x32_bf16(afh[mf], bfh[nf], acc[mf][nf], 0, 0, 0);
            }
    }

    // epilogue: D layout col=lane&15, row=(lane>>4)*4+reg  [m89-verified]
    int r0 = brow + wr * 32 + (lane >> 4) * 4;
    #pragma unroll
    for (int nf = 0; nf < 4; ++nf) {
        int c = bcol + wc * 64 + nf * 16 + rlo;
        float s = 0.f, s2 = 0.f;
        float bv = (MODE == 0) ? bias[c] : 0.f;
        #pragma unroll
        for (int mf = 0; mf < 2; ++mf) {
            #pragma unroll
            for (int reg = 0; reg < 4; ++reg) {
                int rr = r0 + mf * 16 + reg;
                if (rr < M) {
                    float o;
                    if (MODE == 0) {
                        o = fmaxf(acc[mf][nf][reg] + bv, 0.f);
                    } else {
                        size_t pi = (size_t)rr * K + c;   // K == NHID in conv mode
                        float p = bf_to_f(Ah[pi]) + bf_to_f(Al[pi]);
                        o = alpha * acc[mf][nf][reg] + rcoef * p;
                        s += o; s2 = fmaf(o, o, s2);
                    }
                    C[(size_t)rr * NHID + c] = __float2half(o);
                }
            }
        }
        if (MODE == 1) {
            s  += __shfl_xor(s, 16);  s  += __shfl_xor(s, 32);
            s2 += __shfl_xor(s2, 16); s2 += __shfl_xor(s2, 32);
            if (lane < 16) {
                atomicAdd(&stats[c], s);
                atomicAdd(&stats[NHID + c], s2);
            }
        }
    }
}

// ---------------- lin1 GEMM with fused BN+relu on A (A = raw conv output fp16) ----------------
__global__ __launch_bounds__(256)
void gemm_lin1(const __half* __restrict__ A, const float* __restrict__ B,
               const float* __restrict__ bias, float* __restrict__ C,
               const float* __restrict__ stats, const float* __restrict__ g,
               const float* __restrict__ b,
               int M, int Nc, int K) {
    __shared__ float As[16][68];
    __shared__ float Bs[16][68];
    __shared__ float ABs[2][NHID];
    int tid = threadIdx.x;
    {   // build BN affine table once (features = K = 256)
        float mu = stats[tid] * (1.f / N_NODES);
        float var = stats[NHID + tid] * (1.f / N_NODES) - mu * mu;
        float rs = rsqrtf(var + BN_EPS);
        float a = g[tid] * rs;
        ABs[0][tid] = a;
        ABs[1][tid] = b[tid] - mu * a;
    }
    __syncthreads();
    int tc = tid & 15, tr = tid >> 4;
    int brow = blockIdx.x * 64, bcol = blockIdx.y * 64;
    float acc[4][4] = {};
    int arow = tid >> 2;
    int ak = (tid & 3) * 4;
    int bkrow = tid >> 4;
    int bcol4 = (tid & 15) * 4;

    for (int k0 = 0; k0 < K; k0 += 16) {
        int gr = brow + arow;
        float4 av = (gr < M) ? loadh4(A + (size_t)gr * K + k0 + ak)
                             : make_float4(0.f, 0.f, 0.f, 0.f);
        av.x = fmaxf(fmaf(av.x, ABs[0][k0 + ak + 0], ABs[1][k0 + ak + 0]), 0.f);
        av.y = fmaxf(fmaf(av.y, ABs[0][k0 + ak + 1], ABs[1][k0 + ak + 1]), 0.f);
        av.z = fmaxf(fmaf(av.z, ABs[0][k0 + ak + 2], ABs[1][k0 + ak + 2]), 0.f);
        av.w = fmaxf(fmaf(av.w, ABs[0][k0 + ak + 3], ABs[1][k0 + ak + 3]), 0.f);
        As[ak + 0][arow] = av.x;
        As[ak + 1][arow] = av.y;
        As[ak + 2][arow] = av.z;
        As[ak + 3][arow] = av.w;
        float4 bv = *(const float4*)&B[(size_t)(k0 + bkrow) * Nc + bcol + bcol4];
        *(float4*)&Bs[bkrow][bcol4] = bv;
        __syncthreads();
        #pragma unroll
        for (int kk = 0; kk < 16; ++kk) {
            float4 a = *(const float4*)&As[kk][tr * 4];
            float4 b2 = *(const float4*)&Bs[kk][tc * 4];
            acc[0][0] = fmaf(a.x, b2.x, acc[0][0]);
            acc[0][1] = fmaf(a.x, b2.y, acc[0][1]);
            acc[0][2] = fmaf(a.x, b2.z, acc[0][2]);
            acc[0][3] = fmaf(a.x, b2.w, acc[0][3]);
            acc[1][0] = fmaf(a.y, b2.x, acc[1][0]);
            acc[1][1] = fmaf(a.y, b2.y, acc[1][1]);
            acc[1][2] = fmaf(a.y, b2.z, acc[1][2]);
            acc[1][3] = fmaf(a.y, b2.w, acc[1][3]);
            acc[2][0] = fmaf(a.z, b2.x, acc[2][0]);
            acc[2][1] = fmaf(a.z, b2.y, acc[2][1]);
            acc[2][2] = fmaf(a.z, b2.z, acc[2][2]);
            acc[2][3] = fmaf(a.z, b2.w, acc[2][3]);
            acc[3][0] = fmaf(a.w, b2.x, acc[3][0]);
            acc[3][1] = fmaf(a.w, b2.y, acc[3][1]);
            acc[3][2] = fmaf(a.w, b2.z, acc[3][2]);
            acc[3][3] = fmaf(a.w, b2.w, acc[3][3]);
        }
        __syncthreads();
    }

    int r0 = brow + tr * 4, c0 = bcol + tc * 4;
    float4 b4 = *(const float4*)&bias[c0];
    #pragma unroll
    for (int i = 0; i < 4; ++i) {
        int r = r0 + i;
        if (r >= M) continue;
        float4 o;
        o.x = acc[i][0] + b4.x;
        o.y = acc[i][1] + b4.y;
        o.z = acc[i][2] + b4.z;
        o.w = acc[i][3] + b4.w;
        *(float4*)&C[(size_t)r * Nc + c0] = o;
    }
}

// ---------------- host ----------------
static inline size_t align_up(size_t x, size_t a) { return (x + a - 1) & ~(a - 1); }

extern "C" void kernel_launch(void* const* d_in, const int* in_sizes, int n_in,
                              void* d_out, int out_size, void* d_ws, size_t ws_size,
                              hipStream_t stream) {
    const float* x       = (const float*)d_in[0];
    const int*   ei      = (const int*)d_in[1];
    const float* lin0_w  = (const float*)d_in[2];
    const float* lin0_b  = (const float*)d_in[3];
    const float* lin1_w  = (const float*)d_in[4];
    const float* lin1_b  = (const float*)d_in[5];
    const float* conv_w  = (const float*)d_in[6];
    const float* bn_g    = (const float*)d_in[7];
    const float* bn_b    = (const float*)d_in[8];
    const int* rowp = ei;
    const int* colp = ei + N_EDGES;
    float* outp = (float*)d_out;

    char* ws = (char*)d_ws;
    size_t off = 0;
    auto alloc = [&](size_t bytes) { size_t o = off; off = align_up(off + bytes, 256); return ws + o; };
    int*    deg    = (int*)alloc(N_NODES * 4);
    int*    cursor = (int*)alloc(N_NODES * 4);
    int*    offs   = (int*)alloc((N_NODES + 1) * 4);
    float*  dinv   = (float*)alloc(N_NODES * 4);
    int2*   csr    = (int2*)alloc((size_t)N_EDGES * 8);
    __half* x0     = (__half*)alloc((size_t)N_NODES * NHID * 2);
    __half* outb   = (__half*)alloc((size_t)N_NODES * NHID * 2);
    float*  stats  = (float*)alloc(N_LAYERS * 2 * NHID * 4);
    u16*    xh     = (u16*)alloc((size_t)N_NODES * NFEAT * 2);  // reused as p_hi after lin0
    u16*    xl     = (u16*)alloc((size_t)N_NODES * NFEAT * 2);  // reused as p_lo after lin0
    u16*    wh     = (u16*)alloc((size_t)N_LAYERS * NHID * NHID * 2);
    u16*    wl     = (u16*)alloc((size_t)N_LAYERS * NHID * NHID * 2);
    u16*    w0h    = (u16*)alloc((size_t)NFEAT * NHID * 2);
    u16*    w0l    = (u16*)alloc((size_t)NFEAT * NHID * 2);
    (void)ws_size; (void)n_in; (void)in_sizes; (void)out_size;

    // graph preprocessing
    init_kernel<<<40, 256, 0, stream>>>(deg, cursor, stats);
    deg_count<<<(N_EDGES + 255) / 256, 256, 0, stream>>>(colp, deg);
    dinv_kernel<<<(N_NODES + 255) / 256, 256, 0, stream>>>(deg, dinv);
    scan_kernel<<<1, 256, 0, stream>>>(deg, offs);
    scatter_kernel<<<(N_EDGES + 255) / 256, 256, 0, stream>>>(rowp, colp, dinv, offs, cursor, csr);

    // weight + input splits
    convert_w<<<(N_LAYERS * NHID * NHID + NFEAT * NHID + 255) / 256, 256, 0, stream>>>(
        conv_w, wh, wl, lin0_w, w0h, w0l);
    convert_x<<<(N_NODES * NFEAT / 4 + 255) / 256, 256, 0, stream>>>(
        (const float4*)x, (ushort4*)xh, (ushort4*)xl);

    // lin0: x0 = relu(x @ W0 + b0)   [MFMA split-bf16 -> fp16]
    gemm_mfma<0><<<dim3(157, 2), 256, 0, stream>>>(
        xh, xl, w0h, w0l, lin0_b, x0, nullptr, N_NODES, NFEAT, 1.f, 0.f);

    u16* ph = xh;  // alias: x splits no longer needed
    u16* pl = xl;

    for (int l = 0; l < N_LAYERS; ++l) {
        float beta = logf(0.5f / (float)(l + 1) + 1.0f);
        if (l == 0) {
            spmm_blend<0><<<2500, 256, 0, stream>>>(
                x0, x0, offs, csr, dinv, nullptr, nullptr, nullptr,
                (ushort4*)ph, (ushort4*)pl);
        } else {
            spmm_blend<1><<<2500, 256, 0, stream>>>(
                outb, x0, offs, csr, dinv,
                stats + (l - 1) * 2 * NHID, bn_g + (l - 1) * NHID, bn_b + (l - 1) * NHID,
                (ushort4*)ph, (ushort4*)pl);
        }
        gemm_mfma<1><<<dim3(157, 2), 256, 0, stream>>>(
            ph, pl, wh + (size_t)l * NHID * NHID, wl + (size_t)l * NHID * NHID,
            nullptr, outb, stats + l * 2 * NHID, N_NODES, NHID, beta, 1.f - beta);
    }

    // lin1: out = relu_bn(outb_l7) @ W1 + b1  [BN folded into A-load]
    gemm_lin1<<<dim3(157, 1), 256, 0, stream>>>(
        outb, lin1_w, lin1_b, outp,
        stats + 7 * 2 * NHID, bn_g + 7 * NHID, bn_b + 7 * NHID,
        N_NODES, NCLASS, NHID);
}

// Round 13
// 593.271 us; speedup vs baseline: 1.9021x; 1.0134x over previous
//
#include <hip/hip_runtime.h>
#include <hip/hip_fp16.h>
#include <math.h>

#define N_NODES 10000
#define N_EDGES 320000
#define NFEAT 512
#define NHID 256
#define NCLASS 64
#define N_LAYERS 8
#define BN_EPS 1e-5f

typedef unsigned short u16;
typedef __attribute__((ext_vector_type(8))) short short8v;
typedef __attribute__((ext_vector_type(4))) float f32x4;

__device__ __forceinline__ u16 bf_hi_bits(float f) {
    unsigned u = __float_as_uint(f);
    unsigned r = (u + 0x7fffu + ((u >> 16) & 1u)) >> 16;
    return (u16)r;
}
__device__ __forceinline__ float bf_to_f(u16 h) {
    return __uint_as_float(((unsigned)h) << 16);
}
__device__ __forceinline__ float4 loadh4(const __half* p) {
    float2 raw = *(const float2*)p;
    __half2 h0 = *reinterpret_cast<const __half2*>(&raw.x);
    __half2 h1 = *reinterpret_cast<const __half2*>(&raw.y);
    float2 f0 = __half22float2(h0);
    float2 f1 = __half22float2(h1);
    return make_float4(f0.x, f0.y, f1.x, f1.y);
}

// ---------------- init: deg=1 (self loop), cursor=0, stats=0 ----------------
__global__ void init_kernel(int* __restrict__ deg, int* __restrict__ cursor,
                            float* __restrict__ stats) {
    int i = blockIdx.x * 256 + threadIdx.x;
    if (i < N_NODES) { deg[i] = 1; cursor[i] = 0; }
    if (i < N_LAYERS * 2 * NHID) stats[i] = 0.f;
}

__global__ void deg_count(const int* __restrict__ col, int* __restrict__ deg) {
    int e = blockIdx.x * 256 + threadIdx.x;
    if (e < N_EDGES) atomicAdd(&deg[col[e]], 1);
}

// ---------------- blocked scan of (deg-1) -> offs[N+1], fused dinv ----------------
#define SCAN_CHUNK 40
__global__ void scan_kernel(const int* __restrict__ deg, int* __restrict__ offs,
                            float* __restrict__ dinv) {
    __shared__ int tsum[256];
    int tid = threadIdx.x;
    int base = tid * SCAN_CHUNK;
    int local[SCAN_CHUNK];
    int s = 0;
    #pragma unroll
    for (int j = 0; j < SCAN_CHUNK; ++j) {
        int i = base + j;
        int v = 0;
        if (i < N_NODES) {
            int d = deg[i];
            v = d - 1;
            dinv[i] = rsqrtf((float)d);
        }
        local[j] = s;
        s += v;
    }
    tsum[tid] = s;
    __syncthreads();
    #pragma unroll
    for (int off = 1; off < 256; off <<= 1) {
        int v = (tid >= off) ? tsum[tid - off] : 0;
        __syncthreads();
        tsum[tid] += v;
        __syncthreads();
    }
    int carry = (tid > 0) ? tsum[tid - 1] : 0;
    #pragma unroll
    for (int j = 0; j < SCAN_CHUNK; ++j) {
        int i = base + j;
        if (i < N_NODES) offs[i] = carry + local[j];
    }
    if (tid == 255) offs[N_NODES] = tsum[255];
}

__global__ void scatter_kernel(const int* __restrict__ row, const int* __restrict__ col,
                               const float* __restrict__ dinv, const int* __restrict__ offs,
                               int* __restrict__ cursor, int2* __restrict__ csr) {
    int e = blockIdx.x * 256 + threadIdx.x;
    if (e >= N_EDGES) return;
    int c = col[e], r = row[e];
    int pos = offs[c] + atomicAdd(&cursor[c], 1);
    float w = dinv[r] * dinv[c];
    csr[pos] = make_int2(r, __float_as_int(w));
}

// ---------------- merged split conversion: conv_w + lin0_w (transposed) + x ----------------
#define CW_ELEMS (N_LAYERS * NHID * NHID)
#define W0_ELEMS (NFEAT * NHID)
__global__ void convert_all(const float* __restrict__ cw, u16* __restrict__ wh, u16* __restrict__ wl,
                            const float* __restrict__ l0w, u16* __restrict__ w0h, u16* __restrict__ w0l,
                            const float4* __restrict__ x4, ushort4* __restrict__ xh,
                            ushort4* __restrict__ xl) {
    int i = blockIdx.x * 256 + threadIdx.x;
    if (i < CW_ELEMS) {
        int l = i >> 16, rem = i & 65535, n = rem & 255;   // k = rem >> 8
        float f = cw[i];
        u16 h = bf_hi_bits(f); u16 lo = bf_hi_bits(f - bf_to_f(h));
        int o = (l << 16) | (n << 8) | (rem >> 8);
        wh[o] = h; wl[o] = lo;
    } else if (i < CW_ELEMS + W0_ELEMS) {
        int j = i - CW_ELEMS;
        int k = j >> 8, n = j & 255;
        float f = l0w[j];
        u16 h = bf_hi_bits(f); u16 lo = bf_hi_bits(f - bf_to_f(h));
        int o = n * NFEAT + k;
        w0h[o] = h; w0l[o] = lo;
    } else {
        int j = i - (CW_ELEMS + W0_ELEMS);
        if (j < N_NODES * NFEAT / 4) {
            float4 v = x4[j];
            ushort4 h, l;
            h.x = bf_hi_bits(v.x); l.x = bf_hi_bits(v.x - bf_to_f(h.x));
            h.y = bf_hi_bits(v.y); l.y = bf_hi_bits(v.y - bf_to_f(h.y));
            h.z = bf_hi_bits(v.z); l.z = bf_hi_bits(v.z - bf_to_f(h.z));
            h.w = bf_hi_bits(v.w); l.w = bf_hi_bits(v.w - bf_to_f(h.w));
            xh[j] = h; xl[j] = l;
        }
    }
}

// ---------------- fused SpMM: gather src, BN(+relu) on the fly, blend, emit split-bf16 ----------------
// 8-edge unroll (8 loads in flight), 4 accumulator chains.
template<int BN>
__global__ __launch_bounds__(256)
void spmm_blend(const __half* __restrict__ src, const __half* __restrict__ x0b,
                const int* __restrict__ offs, const int2* __restrict__ csr,
                const float* __restrict__ dinv,
                const float* __restrict__ stats, const float* __restrict__ g,
                const float* __restrict__ b,
                ushort4* __restrict__ ph, ushort4* __restrict__ pl) {
    int wid = threadIdx.x >> 6;
    int lane = threadIdx.x & 63;
    int v = blockIdx.x * 4 + wid;
    if (v >= N_NODES) return;
    int f0 = lane * 4;

    float4 A4 = make_float4(1.f, 1.f, 1.f, 1.f);
    float4 B4 = make_float4(0.f, 0.f, 0.f, 0.f);
    if (BN) {
        float4 sv = *(const float4*)&stats[f0];
        float4 qv = *(const float4*)&stats[NHID + f0];
        float4 gv = *(const float4*)&g[f0];
        float4 bv = *(const float4*)&b[f0];
        const float inv = 1.f / N_NODES;
        float mu, var, rs;
        mu = sv.x * inv; var = qv.x * inv - mu * mu; rs = rsqrtf(var + BN_EPS);
        A4.x = gv.x * rs; B4.x = bv.x - mu * A4.x;
        mu = sv.y * inv; var = qv.y * inv - mu * mu; rs = rsqrtf(var + BN_EPS);
        A4.y = gv.y * rs; B4.y = bv.y - mu * A4.y;
        mu = sv.z * inv; var = qv.z * inv - mu * mu; rs = rsqrtf(var + BN_EPS);
        A4.z = gv.z * rs; B4.z = bv.z - mu * A4.z;
        mu = sv.w * inv; var = qv.w * inv - mu * mu; rs = rsqrtf(var + BN_EPS);
        A4.w = gv.w * rs; B4.w = bv.w - mu * A4.w;
    }
    auto tf = [&](float4 r) {
        float4 o;
        if (BN) {
            o.x = fmaxf(fmaf(r.x, A4.x, B4.x), 0.f);
            o.y = fmaxf(fmaf(r.y, A4.y, B4.y), 0.f);
            o.z = fmaxf(fmaf(r.z, A4.z, B4.z), 0.f);
            o.w = fmaxf(fmaf(r.w, A4.w, B4.w), 0.f);
        } else {
            o.x = fmaxf(r.x, 0.f); o.y = fmaxf(r.y, 0.f);
            o.z = fmaxf(r.z, 0.f); o.w = fmaxf(r.w, 0.f);
        }
        return o;
    };

    size_t base = (size_t)v * NHID + f0;
    float dv = dinv[v];
    float sw = dv * dv;
    float4 a0 = tf(loadh4(src + base));    // self loop
    a0.x *= sw; a0.y *= sw; a0.z *= sw; a0.w *= sw;
    float4 a1 = make_float4(0.f, 0.f, 0.f, 0.f);
    float4 a2 = make_float4(0.f, 0.f, 0.f, 0.f);
    float4 a3 = make_float4(0.f, 0.f, 0.f, 0.f);
    int beg = offs[v], end = offs[v + 1];
    int e = beg;
    for (; e + 7 < end; e += 8) {
        int2 s0 = csr[e];
        int2 s1 = csr[e + 1];
        int2 s2 = csr[e + 2];
        int2 s3 = csr[e + 3];
        int2 s4 = csr[e + 4];
        int2 s5 = csr[e + 5];
        int2 s6 = csr[e + 6];
        int2 s7 = csr[e + 7];
        float4 h0 = tf(loadh4(src + (size_t)s0.x * NHID + f0));
        float4 h1 = tf(loadh4(src + (size_t)s1.x * NHID + f0));
        float4 h2 = tf(loadh4(src + (size_t)s2.x * NHID + f0));
        float4 h3 = tf(loadh4(src + (size_t)s3.x * NHID + f0));
        float4 h4 = tf(loadh4(src + (size_t)s4.x * NHID + f0));
        float4 h5 = tf(loadh4(src + (size_t)s5.x * NHID + f0));
        float4 h6 = tf(loadh4(src + (size_t)s6.x * NHID + f0));
        float4 h7 = tf(loadh4(src + (size_t)s7.x * NHID + f0));
        float w0 = __int_as_float(s0.y), w1 = __int_as_float(s1.y);
        float w2 = __int_as_float(s2.y), w3 = __int_as_float(s3.y);
        float w4 = __int_as_float(s4.y), w5 = __int_as_float(s5.y);
        float w6 = __int_as_float(s6.y), w7 = __int_as_float(s7.y);
        a0.x = fmaf(w0, h0.x, a0.x); a1.x = fmaf(w1, h1.x, a1.x);
        a2.x = fmaf(w2, h2.x, a2.x); a3.x = fmaf(w3, h3.x, a3.x);
        a0.y = fmaf(w0, h0.y, a0.y); a1.y = fmaf(w1, h1.y, a1.y);
        a2.y = fmaf(w2, h2.y, a2.y); a3.y = fmaf(w3, h3.y, a3.y);
        a0.z = fmaf(w0, h0.z, a0.z); a1.z = fmaf(w1, h1.z, a1.z);
        a2.z = fmaf(w2, h2.z, a2.z); a3.z = fmaf(w3, h3.z, a3.z);
        a0.w = fmaf(w0, h0.w, a0.w); a1.w = fmaf(w1, h1.w, a1.w);
        a2.w = fmaf(w2, h2.w, a2.w); a3.w = fmaf(w3, h3.w, a3.w);
        a0.x = fmaf(w4, h4.x, a0.x); a1.x = fmaf(w5, h5.x, a1.x);
        a2.x = fmaf(w6, h6.x, a2.x); a3.x = fmaf(w7, h7.x, a3.x);
        a0.y = fmaf(w4, h4.y, a0.y); a1.y = fmaf(w5, h5.y, a1.y);
        a2.y = fmaf(w6, h6.y, a2.y); a3.y = fmaf(w7, h7.y, a3.y);
        a0.z = fmaf(w4, h4.z, a0.z); a1.z = fmaf(w5, h5.z, a1.z);
        a2.z = fmaf(w6, h6.z, a2.z); a3.z = fmaf(w7, h7.z, a3.z);
        a0.w = fmaf(w4, h4.w, a0.w); a1.w = fmaf(w5, h5.w, a1.w);
        a2.w = fmaf(w6, h6.w, a2.w); a3.w = fmaf(w7, h7.w, a3.w);
    }
    for (; e + 3 < end; e += 4) {
        int2 s0 = csr[e];
        int2 s1 = csr[e + 1];
        int2 s2 = csr[e + 2];
        int2 s3 = csr[e + 3];
        float w0 = __int_as_float(s0.y);
        float w1 = __int_as_float(s1.y);
        float w2 = __int_as_float(s2.y);
        float w3 = __int_as_float(s3.y);
        float4 h0 = tf(loadh4(src + (size_t)s0.x * NHID + f0));
        float4 h1 = tf(loadh4(src + (size_t)s1.x * NHID + f0));
        float4 h2 = tf(loadh4(src + (size_t)s2.x * NHID + f0));
        float4 h3 = tf(loadh4(src + (size_t)s3.x * NHID + f0));
        a0.x = fmaf(w0, h0.x, a0.x); a1.x = fmaf(w1, h1.x, a1.x);
        a2.x = fmaf(w2, h2.x, a2.x); a3.x = fmaf(w3, h3.x, a3.x);
        a0.y = fmaf(w0, h0.y, a0.y); a1.y = fmaf(w1, h1.y, a1.y);
        a2.y = fmaf(w2, h2.y, a2.y); a3.y = fmaf(w3, h3.y, a3.y);
        a0.z = fmaf(w0, h0.z, a0.z); a1.z = fmaf(w1, h1.z, a1.z);
        a2.z = fmaf(w2, h2.z, a2.z); a3.z = fmaf(w3, h3.z, a3.z);
        a0.w = fmaf(w0, h0.w, a0.w); a1.w = fmaf(w1, h1.w, a1.w);
        a2.w = fmaf(w2, h2.w, a2.w); a3.w = fmaf(w3, h3.w, a3.w);
    }
    for (; e < end; ++e) {
        int2 s0 = csr[e];
        float w0 = __int_as_float(s0.y);
        float4 h0 = tf(loadh4(src + (size_t)s0.x * NHID + f0));
        a0.x = fmaf(w0, h0.x, a0.x);
        a0.y = fmaf(w0, h0.y, a0.y);
        a0.z = fmaf(w0, h0.z, a0.z);
        a0.w = fmaf(w0, h0.w, a0.w);
    }
    float4 xv = loadh4(x0b + base);
    float4 r;
    r.x = 0.9f * ((a0.x + a1.x) + (a2.x + a3.x)) + 0.1f * xv.x;
    r.y = 0.9f * ((a0.y + a1.y) + (a2.y + a3.y)) + 0.1f * xv.y;
    r.z = 0.9f * ((a0.z + a1.z) + (a2.z + a3.z)) + 0.1f * xv.z;
    r.w = 0.9f * ((a0.w + a1.w) + (a2.w + a3.w)) + 0.1f * xv.w;
    ushort4 hh, ll;
    hh.x = bf_hi_bits(r.x); ll.x = bf_hi_bits(r.x - bf_to_f(hh.x));
    hh.y = bf_hi_bits(r.y); ll.y = bf_hi_bits(r.y - bf_to_f(hh.y));
    hh.z = bf_hi_bits(r.z); ll.z = bf_hi_bits(r.z - bf_to_f(hh.z));
    hh.w = bf_hi_bits(r.w); ll.w = bf_hi_bits(r.w - bf_to_f(hh.w));
    ph[(size_t)v * 64 + lane] = hh;
    pl[(size_t)v * 64 + lane] = ll;
}

// ---------------- split-bf16 MFMA GEMM ----------------
// MODE 0: out = relu(acc + bias)       (lin0 -> x0 fp16)
// MODE 1: out = alpha*acc + rcoef*(Ah+Al); fused BN column sums (fp32, pre-rounding)
template<int MODE>
__global__ __launch_bounds__(256)
void gemm_mfma(const u16* __restrict__ Ah, const u16* __restrict__ Al,
               const u16* __restrict__ BTh, const u16* __restrict__ BTl,
               const float* __restrict__ bias, __half* __restrict__ C,
               float* __restrict__ stats, int M, int K,
               float alpha, float rcoef) {
    __shared__ u16 As_h[64][40], As_l[64][40];
    __shared__ u16 Bs_h[128][40], Bs_l[128][40];
    int tid = threadIdx.x;
    int lane = tid & 63, wid = tid >> 6;
    int wr = wid >> 1, wc = wid & 1;
    int brow = blockIdx.x * 64;
    int bcol = blockIdx.y * 128;

    f32x4 acc[2][4];
    #pragma unroll
    for (int i = 0; i < 2; ++i)
        #pragma unroll
        for (int j = 0; j < 4; ++j) { acc[i][j].x = 0.f; acc[i][j].y = 0.f; acc[i][j].z = 0.f; acc[i][j].w = 0.f; }

    int am = tid >> 2, akc = (tid & 3) * 8;
    int bn = tid >> 1, bkc = (tid & 1) * 16;
    bool aval = (brow + am) < M;
    size_t arow_off = (size_t)(brow + am) * K + akc;
    size_t brow_off = (size_t)(bcol + bn) * K + bkc;
    int rlo = lane & 15, kg = (lane >> 4) * 8;

    for (int k0 = 0; k0 < K; k0 += 32) {
        uint4 z4 = make_uint4(0, 0, 0, 0);
        uint4 a_h = aval ? *(const uint4*)(Ah + arow_off + k0) : z4;
        uint4 a_l = aval ? *(const uint4*)(Al + arow_off + k0) : z4;
        uint4 b_h0 = *(const uint4*)(BTh + brow_off + k0);
        uint4 b_h1 = *(const uint4*)(BTh + brow_off + k0 + 8);
        uint4 b_l0 = *(const uint4*)(BTl + brow_off + k0);
        uint4 b_l1 = *(const uint4*)(BTl + brow_off + k0 + 8);
        __syncthreads();
        *(uint4*)&As_h[am][akc] = a_h;
        *(uint4*)&As_l[am][akc] = a_l;
        *(uint4*)&Bs_h[bn][bkc] = b_h0;
        *(uint4*)&Bs_h[bn][bkc + 8] = b_h1;
        *(uint4*)&Bs_l[bn][bkc] = b_l0;
        *(uint4*)&Bs_l[bn][bkc + 8] = b_l1;
        __syncthreads();

        short8v afh[2], afl[2], bfh[4], bfl[4];
        #pragma unroll
        for (int mf = 0; mf < 2; ++mf) {
            afh[mf] = *(const short8v*)&As_h[wr * 32 + mf * 16 + rlo][kg];
            afl[mf] = *(const short8v*)&As_l[wr * 32 + mf * 16 + rlo][kg];
        }
        #pragma unroll
        for (int nf = 0; nf < 4; ++nf) {
            bfh[nf] = *(const short8v*)&Bs_h[wc * 64 + nf * 16 + rlo][kg];
            bfl[nf] = *(const short8v*)&Bs_l[wc * 64 + nf * 16 + rlo][kg];
        }
        #pragma unroll
        for (int mf = 0; mf < 2; ++mf)
            #pragma unroll
            for (int nf = 0; nf < 4; ++nf) {
                acc[mf][nf] = __builtin_amdgcn_mfma_f32_16x16x32_bf16(afl[mf], bfh[nf], acc[mf][nf], 0, 0, 0);
                acc[mf][nf] = __builtin_amdgcn_mfma_f32_16x16x32_bf16(afh[mf], bfl[nf], acc[mf][nf], 0, 0, 0);
                acc[mf][nf] = __builtin_amdgcn_mfma_f32_16x16x32_bf16(afh[mf], bfh[nf], acc[mf][nf], 0, 0, 0);
            }
    }

    // epilogue: D layout col=lane&15, row=(lane>>4)*4+reg  [m89-verified]
    int r0 = brow + wr * 32 + (lane >> 4) * 4;
    #pragma unroll
    for (int nf = 0; nf < 4; ++nf) {
        int c = bcol + wc * 64 + nf * 16 + rlo;
        float s = 0.f, s2 = 0.f;
        float bv = (MODE == 0) ? bias[c] : 0.f;
        #pragma unroll
        for (int mf = 0; mf < 2; ++mf) {
            #pragma unroll
            for (int reg = 0; reg < 4; ++reg) {
                int rr = r0 + mf * 16 + reg;
                if (rr < M) {
                    float o;
                    if (MODE == 0) {
                        o = fmaxf(acc[mf][nf][reg] + bv, 0.f);
                    } else {
                        size_t pi = (size_t)rr * K + c;   // K == NHID in conv mode
                        float p = bf_to_f(Ah[pi]) + bf_to_f(Al[pi]);
                        o = alpha * acc[mf][nf][reg] + rcoef * p;
                        s += o; s2 = fmaf(o, o, s2);
                    }
                    C[(size_t)rr * NHID + c] = __float2half(o);
                }
            }
        }
        if (MODE == 1) {
            s  += __shfl_xor(s, 16);  s  += __shfl_xor(s, 32);
            s2 += __shfl_xor(s2, 16); s2 += __shfl_xor(s2, 32);
            if (lane < 16) {
                atomicAdd(&stats[c], s);
                atomicAdd(&stats[NHID + c], s2);
            }
        }
    }
}

// ---------------- lin1 GEMM with fused BN+relu on A (A = raw conv output fp16) ----------------
__global__ __launch_bounds__(256)
void gemm_lin1(const __half* __restrict__ A, const float* __restrict__ B,
               const float* __restrict__ bias, float* __restrict__ C,
               const float* __restrict__ stats, const float* __restrict__ g,
               const float* __restrict__ b,
               int M, int Nc, int K) {
    __shared__ float As[16][68];
    __shared__ float Bs[16][68];
    __shared__ float ABs[2][NHID];
    int tid = threadIdx.x;
    {   // build BN affine table once (features = K = 256)
        float mu = stats[tid] * (1.f / N_NODES);
        float var = stats[NHID + tid] * (1.f / N_NODES) - mu * mu;
        float rs = rsqrtf(var + BN_EPS);
        float a = g[tid] * rs;
        ABs[0][tid] = a;
        ABs[1][tid] = b[tid] - mu * a;
    }
    __syncthreads();
    int tc = tid & 15, tr = tid >> 4;
    int brow = blockIdx.x * 64, bcol = blockIdx.y * 64;
    float acc[4][4] = {};
    int arow = tid >> 2;
    int ak = (tid & 3) * 4;
    int bkrow = tid >> 4;
    int bcol4 = (tid & 15) * 4;

    for (int k0 = 0; k0 < K; k0 += 16) {
        int gr = brow + arow;
        float4 av = (gr < M) ? loadh4(A + (size_t)gr * K + k0 + ak)
                             : make_float4(0.f, 0.f, 0.f, 0.f);
        av.x = fmaxf(fmaf(av.x, ABs[0][k0 + ak + 0], ABs[1][k0 + ak + 0]), 0.f);
        av.y = fmaxf(fmaf(av.y, ABs[0][k0 + ak + 1], ABs[1][k0 + ak + 1]), 0.f);
        av.z = fmaxf(fmaf(av.z, ABs[0][k0 + ak + 2], ABs[1][k0 + ak + 2]), 0.f);
        av.w = fmaxf(fmaf(av.w, ABs[0][k0 + ak + 3], ABs[1][k0 + ak + 3]), 0.f);
        As[ak + 0][arow] = av.x;
        As[ak + 1][arow] = av.y;
        As[ak + 2][arow] = av.z;
        As[ak + 3][arow] = av.w;
        float4 bv = *(const float4*)&B[(size_t)(k0 + bkrow) * Nc + bcol + bcol4];
        *(float4*)&Bs[bkrow][bcol4] = bv;
        __syncthreads();
        #pragma unroll
        for (int kk = 0; kk < 16; ++kk) {
            float4 a = *(const float4*)&As[kk][tr * 4];
            float4 b2 = *(const float4*)&Bs[kk][tc * 4];
            acc[0][0] = fmaf(a.x, b2.x, acc[0][0]);
            acc[0][1] = fmaf(a.x, b2.y, acc[0][1]);
            acc[0][2] = fmaf(a.x, b2.z, acc[0][2]);
            acc[0][3] = fmaf(a.x, b2.w, acc[0][3]);
            acc[1][0] = fmaf(a.y, b2.x, acc[1][0]);
            acc[1][1] = fmaf(a.y, b2.y, acc[1][1]);
            acc[1][2] = fmaf(a.y, b2.z, acc[1][2]);
            acc[1][3] = fmaf(a.y, b2.w, acc[1][3]);
            acc[2][0] = fmaf(a.z, b2.x, acc[2][0]);
            acc[2][1] = fmaf(a.z, b2.y, acc[2][1]);
            acc[2][2] = fmaf(a.z, b2.z, acc[2][2]);
            acc[2][3] = fmaf(a.z, b2.w, acc[2][3]);
            acc[3][0] = fmaf(a.w, b2.x, acc[3][0]);
            acc[3][1] = fmaf(a.w, b2.y, acc[3][1]);
            acc[3][2] = fmaf(a.w, b2.z, acc[3][2]);
            acc[3][3] = fmaf(a.w, b2.w, acc[3][3]);
        }
        __syncthreads();
    }

    int r0 = brow + tr * 4, c0 = bcol + tc * 4;
    float4 b4 = *(const float4*)&bias[c0];
    #pragma unroll
    for (int i = 0; i < 4; ++i) {
        int r = r0 + i;
        if (r >= M) continue;
        float4 o;
        o.x = acc[i][0] + b4.x;
        o.y = acc[i][1] + b4.y;
        o.z = acc[i][2] + b4.z;
        o.w = acc[i][3] + b4.w;
        *(float4*)&C[(size_t)r * Nc + c0] = o;
    }
}

// ---------------- host ----------------
static inline size_t align_up(size_t x, size_t a) { return (x + a - 1) & ~(a - 1); }

extern "C" void kernel_launch(void* const* d_in, const int* in_sizes, int n_in,
                              void* d_out, int out_size, void* d_ws, size_t ws_size,
                              hipStream_t stream) {
    const float* x       = (const float*)d_in[0];
    const int*   ei      = (const int*)d_in[1];
    const float* lin0_w  = (const float*)d_in[2];
    const float* lin0_b  = (const float*)d_in[3];
    const float* lin1_w  = (const float*)d_in[4];
    const float* lin1_b  = (const float*)d_in[5];
    const float* conv_w  = (const float*)d_in[6];
    const float* bn_g    = (const float*)d_in[7];
    const float* bn_b    = (const float*)d_in[8];
    const int* rowp = ei;
    const int* colp = ei + N_EDGES;
    float* outp = (float*)d_out;

    char* ws = (char*)d_ws;
    size_t off = 0;
    auto alloc = [&](size_t bytes) { size_t o = off; off = align_up(off + bytes, 256); return ws + o; };
    int*    deg    = (int*)alloc(N_NODES * 4);
    int*    cursor = (int*)alloc(N_NODES * 4);
    int*    offs   = (int*)alloc((N_NODES + 1) * 4);
    float*  dinv   = (float*)alloc(N_NODES * 4);
    int2*   csr    = (int2*)alloc((size_t)N_EDGES * 8);
    __half* x0     = (__half*)alloc((size_t)N_NODES * NHID * 2);
    __half* outb   = (__half*)alloc((size_t)N_NODES * NHID * 2);
    float*  stats  = (float*)alloc(N_LAYERS * 2 * NHID * 4);
    u16*    xh     = (u16*)alloc((size_t)N_NODES * NFEAT * 2);  // reused as p_hi after lin0
    u16*    xl     = (u16*)alloc((size_t)N_NODES * NFEAT * 2);  // reused as p_lo after lin0
    u16*    wh     = (u16*)alloc((size_t)N_LAYERS * NHID * NHID * 2);
    u16*    wl     = (u16*)alloc((size_t)N_LAYERS * NHID * NHID * 2);
    u16*    w0h    = (u16*)alloc((size_t)NFEAT * NHID * 2);
    u16*    w0l    = (u16*)alloc((size_t)NFEAT * NHID * 2);
    (void)ws_size; (void)n_in; (void)in_sizes; (void)out_size;

    // graph preprocessing
    init_kernel<<<40, 256, 0, stream>>>(deg, cursor, stats);
    deg_count<<<(N_EDGES + 255) / 256, 256, 0, stream>>>(colp, deg);
    scan_kernel<<<1, 256, 0, stream>>>(deg, offs, dinv);
    scatter_kernel<<<(N_EDGES + 255) / 256, 256, 0, stream>>>(rowp, colp, dinv, offs, cursor, csr);

    // merged weight + input splits
    int conv_elems = CW_ELEMS + W0_ELEMS + N_NODES * NFEAT / 4;
    convert_all<<<(conv_elems + 255) / 256, 256, 0, stream>>>(
        conv_w, wh, wl, lin0_w, w0h, w0l,
        (const float4*)x, (ushort4*)xh, (ushort4*)xl);

    // lin0: x0 = relu(x @ W0 + b0)   [MFMA split-bf16 -> fp16]
    gemm_mfma<0><<<dim3(157, 2), 256, 0, stream>>>(
        xh, xl, w0h, w0l, lin0_b, x0, nullptr, N_NODES, NFEAT, 1.f, 0.f);

    u16* ph = xh;  // alias: x splits no longer needed
    u16* pl = xl;

    for (int l = 0; l < N_LAYERS; ++l) {
        float beta = logf(0.5f / (float)(l + 1) + 1.0f);
        if (l == 0) {
            spmm_blend<0><<<2500, 256, 0, stream>>>(
                x0, x0, offs, csr, dinv, nullptr, nullptr, nullptr,
                (ushort4*)ph, (ushort4*)pl);
        } else {
            spmm_blend<1><<<2500, 256, 0, stream>>>(
                outb, x0, offs, csr, dinv,
                stats + (l - 1) * 2 * NHID, bn_g + (l - 1) * NHID, bn_b + (l - 1) * NHID,
                (ushort4*)ph, (ushort4*)pl);
        }
        gemm_mfma<1><<<dim3(157, 2), 256, 0, stream>>>(
            ph, pl, wh + (size_t)l * NHID * NHID, wl + (size_t)l * NHID * NHID,
            nullptr, outb, stats + l * 2 * NHID, N_NODES, NHID, beta, 1.f - beta);
    }

    // lin1: out = relu_bn(outb_l7) @ W1 + b1  [BN folded into A-load]
    gemm_lin1<<<dim3(157, 1), 256, 0, stream>>>(
        outb, lin1_w, lin1_b, outp,
        stats + 7 * 2 * NHID, bn_g + 7 * NHID, bn_b + 7 * NHID,
        N_NODES, NCLASS, NHID);
}